// Round 14
// baseline (1445.747 us; speedup 1.0000x reference)
//
#include <hip/hip_runtime.h>
#include <cstdint>

#define NPTS 131072
#define NB 64
#define MAXPB 2560
#define MT 128
#define TD 768
#define CAND 160
#define MC (NB * CAND)   // 10240 candidate rows

typedef _Float16 f16;
typedef _Float16 f16x8 __attribute__((ext_vector_type(8)));
typedef float f32x4 __attribute__((ext_vector_type(4)));

__device__ __forceinline__ uint32_t pk2(float a, float b) {
    f16 ha = (f16)a, hb = (f16)b;
    return (uint32_t)__builtin_bit_cast(unsigned short, ha) |
           ((uint32_t)__builtin_bit_cast(unsigned short, hb) << 16);
}

// float -> order-preserving u32 (unsigned asc == float asc)
__device__ __forceinline__ uint32_t sortable(float f) {
    uint32_t u = __builtin_bit_cast(uint32_t, f);
    return u ^ (uint32_t)(((int32_t)u >> 31) | 0x80000000);
}

// direct HBM -> LDS, 16B per lane. LDS dest = wave-uniform base + lane*16.
__device__ __forceinline__ void gload16(const void* g, void* l) {
    __builtin_amdgcn_global_load_lds(
        (const __attribute__((address_space(1))) uint32_t*)g,
        (__attribute__((address_space(3))) uint32_t*)l,
        16, 0, 0);
}

// ---------------------------------------------------------------------------
// offsets via binary search on sorted batch_ids
// ---------------------------------------------------------------------------
__global__ void k_counts(const int* __restrict__ bids, int* __restrict__ offs)
{
    int b = threadIdx.x;
    if (b > NB) return;
    int lo = 0, hi = NPTS;
    while (lo < hi) { int mid = (lo + hi) >> 1; if (bids[mid] < b) lo = mid + 1; else hi = mid; }
    offs[b] = lo;
}

// ---------------------------------------------------------------------------
// weight cast: W[K][N] fp32 -> Wt[N][Kpad] f16 (zero-padded K)
// ---------------------------------------------------------------------------
__global__ __launch_bounds__(256) void k_cvtw(const float* __restrict__ W,
                                              unsigned short* __restrict__ out,
                                              int K, int N, int Kpad)
{
    int i = blockIdx.x * 256 + threadIdx.x;
    if (i >= N * Kpad) return;
    int n = i / Kpad, k = i % Kpad;
    f16 v = (f16)0.f;
    if (k < K) v = (f16)W[(size_t)k * N + n];
    out[i] = __builtin_bit_cast(unsigned short, v);
}

// fused head bias: bf[n] = hb1[n] + sum_j mb4[j] * hw1[j][n]   (n < 384)
__global__ void k_fuseb(const float* __restrict__ mb4, const float* __restrict__ hw1,
                        const float* __restrict__ hb1, float* __restrict__ bf)
{
    int n = blockIdx.x * 128 + threadIdx.x;
    if (n >= 384) return;
    float s = hb1[n];
    for (int j = 0; j < 768; ++j) s = fmaf(mb4[j], hw1[(size_t)j * 384 + n], s);
    bf[n] = s;
}

// ---------------------------------------------------------------------------
// Per-point front-end, f16 output [M][128] = [feat32, sp64, pad32].
// Also initializes scores[p] = hb2 (accumulated by fused L4' epilogue).
// ---------------------------------------------------------------------------
__global__ __launch_bounds__(256) void k_x96h(
    const float* __restrict__ coords, const float* __restrict__ feats,
    const float* __restrict__ times,
    const float* __restrict__ ln_g, const float* __restrict__ ln_b,
    const float* __restrict__ sw1, const float* __restrict__ sb1,
    const float* __restrict__ sw2, const float* __restrict__ sb2,
    const float* __restrict__ hb2, float* __restrict__ scores,
    int p0, int M, unsigned short* __restrict__ X)
{
    __shared__ float w1[256], w2[4096], b1[64], b2[64];
    int t = threadIdx.x;
    w1[t] = sw1[t];
    for (int i = t; i < 4096; i += 256) w2[i] = sw2[i];
    if (t < 64) { b1[t] = sb1[t]; b2[t] = sb2[t]; }
    __syncthreads();

    int r = blockIdx.x * 256 + t;
    if (r >= M) return;
    int p = p0 + r;
    scores[p] = hb2[0];
    unsigned short* out = X + (size_t)r * 128;

    float x0 = coords[(size_t)p*3+0], x1 = coords[(size_t)p*3+1];
    float x2 = coords[(size_t)p*3+2], x3 = times[p];
    float mu = 0.25f*(x0+x1+x2+x3);
    float d0 = x0-mu, d1 = x1-mu, d2 = x2-mu, d3 = x3-mu;
    float var = 0.25f*(d0*d0+d1*d1+d2*d2+d3*d3);
    float inv = 1.0f / sqrtf(var + 1e-5f);
    float xn0 = d0*inv*ln_g[0]+ln_b[0];
    float xn1 = d1*inv*ln_g[1]+ln_b[1];
    float xn2 = d2*inv*ln_g[2]+ln_b[2];
    float xn3 = d3*inv*ln_g[3]+ln_b[3];

    float s1[64];
    #pragma unroll
    for (int j = 0; j < 64; ++j) {
        float a = b1[j];
        a = fmaf(xn0, w1[j],       a);
        a = fmaf(xn1, w1[64 + j],  a);
        a = fmaf(xn2, w1[128 + j], a);
        a = fmaf(xn3, w1[192 + j], a);
        s1[j] = fmaxf(a, 0.f);
    }
    #pragma unroll
    for (int j = 0; j < 32; j += 8) {
        float4 f0 = *(const float4*)(feats + (size_t)p*32 + j);
        float4 f1 = *(const float4*)(feats + (size_t)p*32 + j + 4);
        uint4 u = make_uint4(pk2(f0.x,f0.y), pk2(f0.z,f0.w),
                             pk2(f1.x,f1.y), pk2(f1.z,f1.w));
        *(uint4*)(out + j) = u;
    }
    for (int j0 = 0; j0 < 64; j0 += 8) {
        float a[8];
        #pragma unroll
        for (int i = 0; i < 8; ++i) a[i] = b2[j0+i];
        #pragma unroll
        for (int k = 0; k < 64; ++k) {
            float s = s1[k];
            const float* wr = &w2[k*64 + j0];
            #pragma unroll
            for (int i = 0; i < 8; ++i) a[i] = fmaf(s, wr[i], a[i]);
        }
        #pragma unroll
        for (int i = 0; i < 8; ++i) a[i] = fmaxf(a[i], 0.f);
        uint4 u = make_uint4(pk2(a[0],a[1]), pk2(a[2],a[3]),
                             pk2(a[4],a[5]), pk2(a[6],a[7]));
        *(uint4*)(out + 32 + j0) = u;
    }
    uint4 z = make_uint4(0,0,0,0);
    *(uint4*)(out + 96)  = z;
    *(uint4*)(out + 104) = z;
    *(uint4*)(out + 112) = z;
    *(uint4*)(out + 120) = z;
}

// ---------------------------------------------------------------------------
// Per-point front-end, FP32 output, gather variant (rescore pass)
// ---------------------------------------------------------------------------
__global__ __launch_bounds__(256) void k_x96f(
    const float* __restrict__ coords, const float* __restrict__ feats,
    const float* __restrict__ times,
    const float* __restrict__ ln_g, const float* __restrict__ ln_b,
    const float* __restrict__ sw1, const float* __restrict__ sb1,
    const float* __restrict__ sw2, const float* __restrict__ sb2,
    const int* __restrict__ sel, int M, float* __restrict__ X96)
{
    __shared__ float w1[256], w2[4096], b1[64], b2[64];
    int t = threadIdx.x;
    w1[t] = sw1[t];
    for (int i = t; i < 4096; i += 256) w2[i] = sw2[i];
    if (t < 64) { b1[t] = sb1[t]; b2[t] = sb2[t]; }
    __syncthreads();

    int r = blockIdx.x * 256 + t;
    if (r >= M) return;
    int p = sel[r];
    float* out = X96 + (size_t)r * 96;
    if (p < 0) {
        for (int j = 0; j < 96; j += 4) *(float4*)(out + j) = make_float4(0.f,0.f,0.f,0.f);
        return;
    }
    float x0 = coords[(size_t)p*3+0], x1 = coords[(size_t)p*3+1];
    float x2 = coords[(size_t)p*3+2], x3 = times[p];
    float mu = 0.25f*(x0+x1+x2+x3);
    float d0 = x0-mu, d1 = x1-mu, d2 = x2-mu, d3 = x3-mu;
    float var = 0.25f*(d0*d0+d1*d1+d2*d2+d3*d3);
    float inv = 1.0f / sqrtf(var + 1e-5f);
    float xn0 = d0*inv*ln_g[0]+ln_b[0];
    float xn1 = d1*inv*ln_g[1]+ln_b[1];
    float xn2 = d2*inv*ln_g[2]+ln_b[2];
    float xn3 = d3*inv*ln_g[3]+ln_b[3];

    float s1[64];
    #pragma unroll
    for (int j = 0; j < 64; ++j) {
        float a = b1[j];
        a = fmaf(xn0, w1[j],       a);
        a = fmaf(xn1, w1[64 + j],  a);
        a = fmaf(xn2, w1[128 + j], a);
        a = fmaf(xn3, w1[192 + j], a);
        s1[j] = fmaxf(a, 0.f);
    }
    #pragma unroll
    for (int j = 0; j < 32; j += 4)
        *(float4*)(out + j) = *(const float4*)(feats + (size_t)p*32 + j);

    for (int j0 = 0; j0 < 64; j0 += 4) {
        float a0 = b2[j0+0], a1 = b2[j0+1], a2 = b2[j0+2], a3 = b2[j0+3];
        #pragma unroll
        for (int k = 0; k < 64; ++k) {
            float s = s1[k];
            const float* wr = &w2[k*64 + j0];
            a0 = fmaf(s, wr[0], a0);
            a1 = fmaf(s, wr[1], a1);
            a2 = fmaf(s, wr[2], a2);
            a3 = fmaf(s, wr[3], a3);
        }
        *(float4*)(out + 32 + j0) =
            make_float4(fmaxf(a0,0.f), fmaxf(a1,0.f), fmaxf(a2,0.f), fmaxf(a3,0.f));
    }
}

// ---------------------------------------------------------------------------
// Pure-f16 MFMA GEMM 128x128 (scoring): O = act(A @ Bt^T + b), f16 out.
// If scores != nullptr: fused head — no O writes; per row atomicAdd of
// sum_col relu(acc+b)*hw2[col] into scores[row].
// ---------------------------------------------------------------------------
__global__ __launch_bounds__(256, 3) void k_hgemm(
    const unsigned short* __restrict__ A, const unsigned short* __restrict__ Bt,
    const float* __restrict__ bias, unsigned short* __restrict__ O,
    const float* __restrict__ hw2, float* __restrict__ scores,
    int M, int K, int N, int relu)
{
    __shared__ unsigned short sA[128*64];
    __shared__ unsigned short sB[128*64];
    const int tid = threadIdx.x;
    const int bm = blockIdx.y, bn = blockIdx.x;
    const int lane = tid & 63, w = tid >> 6;
    const int wm = w >> 1, wn = w & 1;
    const int lr = lane & 15, lg = lane >> 4;

    const int srow = lane >> 3;                 // 0..7 == r&7 within chunk
    const int sblk = (lane & 7) ^ srow;         // pre-swizzled source block
    const unsigned short* ga0 = A  + ((size_t)(bm*128 + w*32 + srow)) * K + sblk*8;
    const unsigned short* gb0 = Bt + ((size_t)(bn*128 + w*32 + srow)) * K + sblk*8;

    f32x4 acc[4][4];
    #pragma unroll
    for (int m = 0; m < 4; ++m)
        #pragma unroll
        for (int n = 0; n < 4; ++n) acc[m][n] = (f32x4){0.f,0.f,0.f,0.f};

    for (int kt = 0; kt < K; kt += 64) {
        #pragma unroll
        for (int i = 0; i < 4; ++i) {
            gload16(ga0 + kt + (size_t)(i*8)*K, sA + (w*32 + i*8)*64);
            gload16(gb0 + kt + (size_t)(i*8)*K, sB + (w*32 + i*8)*64);
        }
        __syncthreads();

        #pragma unroll
        for (int kk = 0; kk < 64; kk += 32) {
            const int jj = lg + (kk >> 3);
            f16x8 af[4], bf[4];
            #pragma unroll
            for (int m = 0; m < 4; ++m) {
                int r = wm*64 + m*16 + lr;
                af[m] = *(const f16x8*)&sA[r*64 + ((jj ^ (r & 7)) << 3)];
            }
            #pragma unroll
            for (int n = 0; n < 4; ++n) {
                int r = wn*64 + n*16 + lr;
                bf[n] = *(const f16x8*)&sB[r*64 + ((jj ^ (r & 7)) << 3)];
            }
            #pragma unroll
            for (int m = 0; m < 4; ++m)
                #pragma unroll
                for (int n = 0; n < 4; ++n)
                    acc[m][n] = __builtin_amdgcn_mfma_f32_16x16x32_f16(af[m], bf[n], acc[m][n], 0, 0, 0);
        }
        __syncthreads();
    }

    if (scores) {
        float part[4][4];
        #pragma unroll
        for (int m = 0; m < 4; ++m)
            #pragma unroll
            for (int q = 0; q < 4; ++q) part[m][q] = 0.f;
        #pragma unroll
        for (int n = 0; n < 4; ++n) {
            int colg = bn*128 + wn*64 + n*16 + lr;
            float bb = bias[colg];
            float wv = hw2[colg];
            #pragma unroll
            for (int m = 0; m < 4; ++m)
                #pragma unroll
                for (int q = 0; q < 4; ++q) {
                    float v = fmaxf(acc[m][n][q] + bb, 0.f);
                    part[m][q] = fmaf(v, wv, part[m][q]);
                }
        }
        #pragma unroll
        for (int m = 0; m < 4; ++m)
            #pragma unroll
            for (int q = 0; q < 4; ++q) {
                float s = part[m][q];
                s += __shfl_xor(s, 1);
                s += __shfl_xor(s, 2);
                s += __shfl_xor(s, 4);
                s += __shfl_xor(s, 8);
                if (lr == 0)
                    atomicAdd(&scores[bm*128 + wm*64 + m*16 + lg*4 + q], s);
            }
        return;
    }

    #pragma unroll
    for (int n = 0; n < 4; ++n) {
        int col = bn*128 + wn*64 + n*16 + lr;
        float bb = bias[col];
        #pragma unroll
        for (int m = 0; m < 4; ++m) {
            int row0 = bm*128 + wm*64 + m*16 + lg*4;
            #pragma unroll
            for (int q = 0; q < 4; ++q) {
                float v = acc[m][n][q] + bb;
                if (relu) v = fmaxf(v, 0.f);
                f16 h = (f16)v;
                O[(size_t)(row0 + q) * N + col] = __builtin_bit_cast(unsigned short, h);
            }
        }
    }
}

// ---------------------------------------------------------------------------
// Pure-f16 MFMA GEMM 128x256 tile, 8 waves (2x4) — for N multiple of 256.
// ---------------------------------------------------------------------------
__global__ __launch_bounds__(512) void k_hgemm2(
    const unsigned short* __restrict__ A, const unsigned short* __restrict__ Bt,
    const float* __restrict__ bias, unsigned short* __restrict__ O,
    int M, int K, int N, int relu)
{
    __shared__ unsigned short sA[128*64];   // 16 KiB
    __shared__ unsigned short sB[256*64];   // 32 KiB
    const int tid = threadIdx.x;
    const int bm = blockIdx.y, bn = blockIdx.x;
    const int lane = tid & 63, w = tid >> 6;      // 8 waves
    const int wm = w >> 2, wn = w & 3;            // 2 x 4 wave grid
    const int lr = lane & 15, lg = lane >> 4;

    const int srow = lane >> 3;
    const int sblk = (lane & 7) ^ srow;

    const unsigned short* gsrc[6];
    unsigned short* ldst[6];
    #pragma unroll
    for (int i = 0; i < 6; ++i) {
        int c = w * 6 + i;                        // wave-uniform
        if (c < 16) {
            gsrc[i] = A + (size_t)(bm*128 + c*8 + srow) * K + sblk*8;
            ldst[i] = sA + c*8*64;
        } else {
            gsrc[i] = Bt + (size_t)(bn*256 + (c-16)*8 + srow) * K + sblk*8;
            ldst[i] = sB + (size_t)(c-16)*8*64;
        }
    }

    f32x4 acc[4][4];
    #pragma unroll
    for (int m = 0; m < 4; ++m)
        #pragma unroll
        for (int n = 0; n < 4; ++n) acc[m][n] = (f32x4){0.f,0.f,0.f,0.f};

    for (int kt = 0; kt < K; kt += 64) {
        #pragma unroll
        for (int i = 0; i < 6; ++i) gload16(gsrc[i] + kt, ldst[i]);
        __syncthreads();

        #pragma unroll
        for (int kk = 0; kk < 64; kk += 32) {
            const int jj = lg + (kk >> 3);
            f16x8 af[4], bf[4];
            #pragma unroll
            for (int m = 0; m < 4; ++m) {
                int r = wm*64 + m*16 + lr;
                af[m] = *(const f16x8*)&sA[r*64 + ((jj ^ (r & 7)) << 3)];
            }
            #pragma unroll
            for (int n = 0; n < 4; ++n) {
                int r = wn*64 + n*16 + lr;
                bf[n] = *(const f16x8*)&sB[r*64 + ((jj ^ (r & 7)) << 3)];
            }
            #pragma unroll
            for (int m = 0; m < 4; ++m)
                #pragma unroll
                for (int n = 0; n < 4; ++n)
                    acc[m][n] = __builtin_amdgcn_mfma_f32_16x16x32_f16(af[m], bf[n], acc[m][n], 0, 0, 0);
        }
        __syncthreads();
    }

    #pragma unroll
    for (int n = 0; n < 4; ++n) {
        int col = bn*256 + wn*64 + n*16 + lr;
        float bb = bias[col];
        #pragma unroll
        for (int m = 0; m < 4; ++m) {
            int row0 = bm*128 + wm*64 + m*16 + lg*4;
            #pragma unroll
            for (int q = 0; q < 4; ++q) {
                float v = acc[m][n][q] + bb;
                if (relu) v = fmaxf(v, 0.f);
                f16 h = (f16)v;
                O[(size_t)(row0 + q) * N + col] = __builtin_bit_cast(unsigned short, h);
            }
        }
    }
}

// ---------------------------------------------------------------------------
// fp32 GEMM: BM=128 x BN=64 x BK=32, 4x8/thread.
// Double-buffered LDS + register prefetch: 1 barrier per K-step; next tile's
// global loads issued before the barrier, latency hidden under compute.
// Same FMA order as before => bit-identical results.
// ---------------------------------------------------------------------------
#define BM 128
#define BN 64
#define BK 32

__global__ __launch_bounds__(256, 3) void k_gemm(
    const float* __restrict__ A, const float* __restrict__ W,
    const float* __restrict__ bias, float* __restrict__ C,
    int M, int K, int Nn, int relu)
{
    __shared__ float As[2][BK][BM + 4];   // 2 x 16.9 KiB
    __shared__ float Bs[2][BK][BN];       // 2 x 8.2 KiB   (~50 KiB total)
    const int tid = threadIdx.x;
    const int bm = blockIdx.y, bn = blockIdx.x;
    const int tr = tid >> 3, tc = tid & 7;           // 32x8 threads, 4x8 each
    const int ar0 = tid >> 1, ac0 = (tid & 1) * 16;  // A-stage: 1 row x 4 float4
    const int bk0 = tid >> 3, bn0 = (tid & 7) * 8;   // B-stage: 1 row x 2 float4
    const float* Ab = A + (size_t)bm * BM * K + (size_t)ar0 * K + ac0;
    const float* Wb = W + (size_t)bn * BN + (size_t)bk0 * Nn + bn0;

    float acc[4][8];
    #pragma unroll
    for (int i = 0; i < 4; ++i)
        #pragma unroll
        for (int j = 0; j < 8; ++j) acc[i][j] = 0.f;

    float4 ra0, ra1, ra2, ra3, rw0, rw1;
    ra0 = *(const float4*)(Ab);
    ra1 = *(const float4*)(Ab + 4);
    ra2 = *(const float4*)(Ab + 8);
    ra3 = *(const float4*)(Ab + 12);
    rw0 = *(const float4*)(Wb);
    rw1 = *(const float4*)(Wb + 4);

    const int nt = K / BK;
    for (int t = 0; t < nt; ++t) {
        const int cur = t & 1;
        As[cur][ac0+ 0][ar0] = ra0.x; As[cur][ac0+ 1][ar0] = ra0.y;
        As[cur][ac0+ 2][ar0] = ra0.z; As[cur][ac0+ 3][ar0] = ra0.w;
        As[cur][ac0+ 4][ar0] = ra1.x; As[cur][ac0+ 5][ar0] = ra1.y;
        As[cur][ac0+ 6][ar0] = ra1.z; As[cur][ac0+ 7][ar0] = ra1.w;
        As[cur][ac0+ 8][ar0] = ra2.x; As[cur][ac0+ 9][ar0] = ra2.y;
        As[cur][ac0+10][ar0] = ra2.z; As[cur][ac0+11][ar0] = ra2.w;
        As[cur][ac0+12][ar0] = ra3.x; As[cur][ac0+13][ar0] = ra3.y;
        As[cur][ac0+14][ar0] = ra3.z; As[cur][ac0+15][ar0] = ra3.w;
        *(float4*)&Bs[cur][bk0][bn0]     = rw0;
        *(float4*)&Bs[cur][bk0][bn0 + 4] = rw1;
        if (t + 1 < nt) {
            int k0 = (t + 1) * BK;
            ra0 = *(const float4*)(Ab + k0);
            ra1 = *(const float4*)(Ab + k0 + 4);
            ra2 = *(const float4*)(Ab + k0 + 8);
            ra3 = *(const float4*)(Ab + k0 + 12);
            rw0 = *(const float4*)(Wb + (size_t)k0 * Nn);
            rw1 = *(const float4*)(Wb + (size_t)k0 * Nn + 4);
        }
        __syncthreads();
        #pragma unroll
        for (int kk = 0; kk < BK; ++kk) {
            float4 av  = *(const float4*)&As[cur][kk][tr*4];
            float4 bv0 = *(const float4*)&Bs[cur][kk][tc*8];
            float4 bv1 = *(const float4*)&Bs[cur][kk][tc*8+4];
            float a[4] = {av.x, av.y, av.z, av.w};
            float b[8] = {bv0.x,bv0.y,bv0.z,bv0.w, bv1.x,bv1.y,bv1.z,bv1.w};
            #pragma unroll
            for (int i = 0; i < 4; ++i)
                #pragma unroll
                for (int j = 0; j < 8; ++j)
                    acc[i][j] = fmaf(a[i], b[j], acc[i][j]);
        }
        // no trailing barrier: next iter writes the other buffer; the next
        // barrier orders those writes before anyone computes from them, and
        // every wave reaching it has finished this buffer's compute.
    }

    float bl[8];
    #pragma unroll
    for (int j = 0; j < 8; ++j) bl[j] = bias[(size_t)bn*BN + tc*8 + j];
    #pragma unroll
    for (int i = 0; i < 4; ++i) {
        int row = bm*BM + tr*4 + i;
        float v[8];
        #pragma unroll
        for (int j = 0; j < 8; ++j) {
            float x = acc[i][j] + bl[j];
            v[j] = relu ? fmaxf(x, 0.f) : x;
        }
        float* cr = C + (size_t)row*Nn + bn*BN + tc*8;
        *(float4*)(cr)     = make_float4(v[0],v[1],v[2],v[3]);
        *(float4*)(cr + 4) = make_float4(v[4],v[5],v[6],v[7]);
    }
}

// ---------------------------------------------------------------------------
// score from fp32 T4 (rescore path)
// ---------------------------------------------------------------------------
__global__ __launch_bounds__(256) void k_score(
    const float* __restrict__ T4, const float* __restrict__ hw2,
    const float* __restrict__ hb2, float* __restrict__ scores, int M)
{
    int wv = (blockIdx.x * 256 + threadIdx.x) >> 6;
    int lane = threadIdx.x & 63;
    if (wv >= M) return;
    const float* row = T4 + (size_t)wv * 384;
    float s = 0.f;
    #pragma unroll
    for (int j = 0; j < 384; j += 64) s = fmaf(row[j + lane], hw2[j + lane], s);
    for (int o = 32; o > 0; o >>= 1) s += __shfl_down(s, o, 64);
    if (lane == 0) scores[wv] = s + hb2[0];
}

// ---------------------------------------------------------------------------
// Stage 1 select: per-batch top-CAND via bitonic sort, 1024 threads.
// ---------------------------------------------------------------------------
#define TPAD 4096
__global__ __launch_bounds__(1024) void k_topcand(
    const float* __restrict__ scores, const int* __restrict__ offs,
    int* __restrict__ cand_g, int* __restrict__ cand_p)
{
    __shared__ uint64_t key[TPAD];   // 32 KiB
    int b = blockIdx.x, t = threadIdx.x;
    int off = offs[b];
    int cnt = min(offs[b+1] - off, MAXPB);

    for (int i = t; i < TPAD; i += 1024) {
        uint64_t k = 0;
        if (i < cnt)
            k = ((uint64_t)sortable(scores[off + i]) << 32) | (uint32_t)(~i);
        key[i] = k;
    }

    for (int ksz = 2; ksz <= TPAD; ksz <<= 1) {
        for (int j = ksz >> 1; j > 0; j >>= 1) {
            __syncthreads();
            #pragma unroll 2
            for (int i = t; i < TPAD; i += 1024) {
                int ix = i ^ j;
                if (ix > i) {
                    uint64_t a = key[i], c = key[ix];
                    bool up = (i & ksz) == 0;
                    if (up ? (a < c) : (a > c)) { key[i] = c; key[ix] = a; }
                }
            }
        }
    }
    __syncthreads();

    if (t < CAND) {
        if (t < cnt) {
            int pos = (int)(~(uint32_t)key[t]);
            cand_g[b*CAND + t] = off + pos;
            cand_p[b*CAND + t] = pos;
        } else {
            cand_g[b*CAND + t] = -1;
            cand_p[b*CAND + t] = MAXPB + t;
        }
    }
}

// ---------------------------------------------------------------------------
// Stage 2: final top-MT by fp32 score via bitonic.
// ---------------------------------------------------------------------------
__global__ __launch_bounds__(256) void k_fsel(
    const float* __restrict__ fscores, const int* __restrict__ offs,
    const int* __restrict__ cand_g, const int* __restrict__ cand_p,
    const float* __restrict__ coords, const float* __restrict__ times,
    int* __restrict__ tok_src, float* __restrict__ out_cent,
    float* __restrict__ out_mask)
{
    __shared__ uint64_t key[256];
    int b = blockIdx.x, t = threadIdx.x;
    int cnt = min(offs[b+1] - offs[b], MAXPB);
    int cntc = min(cnt, CAND);

    uint64_t k = 0;
    if (t < cntc) {
        uint32_t s32 = sortable(fscores[b*CAND + t]);
        uint32_t pos = (uint32_t)cand_p[b*CAND + t];
        k = ((uint64_t)s32 << 32) | (((~pos) & 0xFFFu) << 8) | (uint32_t)t;
    }
    key[t] = k;

    for (int ksz = 2; ksz <= 256; ksz <<= 1) {
        for (int j = ksz >> 1; j > 0; j >>= 1) {
            __syncthreads();
            int ix = t ^ j;
            if (ix > t) {
                uint64_t a = key[t], c = key[ix];
                bool up = (t & ksz) == 0;
                if (up ? (a < c) : (a > c)) { key[t] = c; key[ix] = a; }
            }
        }
    }
    __syncthreads();

    if (t < MT) {
        if (t < cntc) {
            int j = (int)(key[t] & 0xFF);
            int row = b*CAND + j;
            int g = cand_g[row];
            tok_src[b*MT + t] = row;
            out_mask[b*MT + t] = 1.0f;
            *(float4*)&out_cent[(size_t)(b*MT + t) * 4] =
                make_float4(coords[(size_t)g*3+0], coords[(size_t)g*3+1],
                            coords[(size_t)g*3+2], times[g]);
        } else {
            tok_src[b*MT + t] = -1;
            out_mask[b*MT + t] = 0.0f;
            *(float4*)&out_cent[(size_t)(b*MT + t) * 4] = make_float4(0.f,0.f,0.f,0.f);
        }
    }
}

// gather tokens from candidate point_feats
__global__ __launch_bounds__(256) void k_tokens(const float* __restrict__ PFc,
                                                const int* __restrict__ tok_src,
                                                float* __restrict__ out)
{
    int i = blockIdx.x * 256 + threadIdx.x;   // 8192*192 float4
    int row = i / 192, c = i % 192;
    int src = tok_src[row];
    float4 v = make_float4(0.f,0.f,0.f,0.f);
    if (src >= 0) v = ((const float4*)PFc)[(size_t)src*192 + c];
    ((float4*)out)[(size_t)row*192 + c] = v;
}

// ---------------------------------------------------------------------------
extern "C" void kernel_launch(void* const* d_in, const int* in_sizes, int n_in,
                              void* d_out, int out_size, void* d_ws, size_t ws_size,
                              hipStream_t stream)
{
    const float* coords = (const float*)d_in[0];
    const float* feats  = (const float*)d_in[1];
    const float* times  = (const float*)d_in[2];
    const int*   bids   = (const int*)  d_in[3];
    const float* ln_g = (const float*)d_in[4];
    const float* ln_b = (const float*)d_in[5];
    const float* sw1  = (const float*)d_in[6];
    const float* sb1  = (const float*)d_in[7];
    const float* sw2  = (const float*)d_in[8];
    const float* sb2  = (const float*)d_in[9];
    const float* mw1  = (const float*)d_in[10];
    const float* mb1  = (const float*)d_in[11];
    const float* mw2  = (const float*)d_in[12];
    const float* mb2  = (const float*)d_in[13];
    const float* mw3  = (const float*)d_in[14];
    const float* mb3  = (const float*)d_in[15];
    const float* mw4  = (const float*)d_in[16];
    const float* mb4  = (const float*)d_in[17];
    const float* hw1  = (const float*)d_in[18];
    const float* hb1  = (const float*)d_in[19];
    const float* hw2  = (const float*)d_in[20];
    const float* hb2  = (const float*)d_in[21];

    float* out_tok  = (float*)d_out;
    float* out_cent = out_tok + (size_t)NB*MT*TD;
    float* out_mask = out_cent + (size_t)NB*MT*4;

    char* wsb = (char*)d_ws;
    size_t off = 0;
    auto alloc = [&](size_t bytes) {
        char* p = wsb + off;
        off = (off + bytes + 255) & ~(size_t)255;
        return p;
    };
    auto mx = [](size_t a, size_t b) { return a > b ? a : b; };

    int*   offs    = (int*)  alloc((NB + 1) * 4);
    float* scores  = (float*)alloc((size_t)NPTS * 4);
    float* fscores = (float*)alloc((size_t)MC * 4);
    int*   cand_g  = (int*)  alloc((size_t)MC * 4);
    int*   cand_p  = (int*)  alloc((size_t)MC * 4);
    int*   tok_src = (int*)  alloc((size_t)NB * MT * 4);
    unsigned short* wt1h = (unsigned short*)alloc((size_t)256 * 128 * 2);
    unsigned short* wt2h = (unsigned short*)alloc((size_t)512 * 256 * 2);
    unsigned short* wt3h = (unsigned short*)alloc((size_t)768 * 512 * 2);
    float* zero384 = (float*)alloc(384 * 4);
    float* wfused  = (float*)alloc((size_t)768 * 384 * 4);   // W' = mw4@hw1 (fp32)
    float* bfused  = (float*)alloc(384 * 4);                 // b' = mb4@hw1 + hb1
    unsigned short* wfh = (unsigned short*)alloc((size_t)384 * 768 * 2);  // W'^T f16
    size_t base = off;

    int Nc = 8192;
    const int cands[3] = {32768, 16384, 8192};
    for (int ci = 0; ci < 3; ++ci) {
        size_t n = cands[ci];
        size_t need = base
            + mx(n*128*2, (size_t)MC*96*4)
            + mx(n*256*2, (size_t)MC*256*4)
            + mx(n*512*2, (size_t)MC*512*4)
            + 2 * mx(n*768*2, (size_t)MC*768*4)
            + 6*256;
        if (need <= ws_size) { Nc = (int)n; break; }
    }
    char* B0 = alloc(mx((size_t)Nc*128*2, (size_t)MC*96*4));
    char* B1 = alloc(mx((size_t)Nc*256*2, (size_t)MC*256*4));
    char* B2 = alloc(mx((size_t)Nc*512*2, (size_t)MC*512*4));
    char* B3 = alloc(mx((size_t)Nc*768*2, (size_t)MC*768*4));
    char* B4 = alloc(mx((size_t)Nc*768*2, (size_t)MC*768*4));

    // ---------- setup ----------
    k_counts<<<1, 128, 0, stream>>>(bids, offs);
    k_cvtw<<<(256*128+255)/256, 256, 0, stream>>>(mw1, wt1h,  96, 256, 128);
    k_cvtw<<<(512*256+255)/256, 256, 0, stream>>>(mw2, wt2h, 256, 512, 256);
    k_cvtw<<<(768*512+255)/256, 256, 0, stream>>>(mw3, wt3h, 512, 768, 512);
    // fused head: W' = mw4 @ hw1 (768x384), b' = mb4 @ hw1 + hb1
    hipMemsetAsync(zero384, 0, 384 * 4, stream);
    k_gemm<<<dim3(6, 6), 256, 0, stream>>>(mw4, hw1, zero384, wfused, 768, 768, 384, 0);
    k_fuseb<<<3, 128, 0, stream>>>(mb4, hw1, hb1, bfused);
    k_cvtw<<<(384*768+255)/256, 256, 0, stream>>>(wfused, wfh, 768, 384, 768);

    // ---------- stage 1: pure-f16 MFMA scoring (mw4+hw1 folded, fused head) --
    {
        unsigned short* X   = (unsigned short*)B0;   // [Nc][128]
        unsigned short* H1h = (unsigned short*)B1;   // [Nc][256]
        unsigned short* H2h = (unsigned short*)B2;   // [Nc][512]
        unsigned short* H3h = (unsigned short*)B3;   // [Nc][768]
        for (int p0 = 0; p0 < NPTS; p0 += Nc) {
            int Mi = min(Nc, NPTS - p0);
            k_x96h<<<(Mi+255)/256, 256, 0, stream>>>(coords, feats, times, ln_g, ln_b,
                                                     sw1, sb1, sw2, sb2, hb2,
                                                     scores, p0, Mi, X);
            k_hgemm <<<dim3(2, Mi/128), 256, 0, stream>>>(X,   wt1h, mb1, H1h,
                                                          nullptr, nullptr, Mi, 128, 256, 1);
            k_hgemm2<<<dim3(2, Mi/128), 512, 0, stream>>>(H1h, wt2h, mb2, H2h, Mi, 256, 512, 1);
            k_hgemm2<<<dim3(3, Mi/128), 512, 0, stream>>>(H2h, wt3h, mb3, H3h, Mi, 512, 768, 1);
            k_hgemm <<<dim3(3, Mi/128), 256, 0, stream>>>(H3h, wfh,  bfused, nullptr,
                                                          hw2, scores + p0, Mi, 768, 384, 1);
        }
    }

    // ---------- stage 2: capture top-CAND per batch (bitonic, 1024 thr) ------
    k_topcand<<<NB, 1024, 0, stream>>>(scores, offs, cand_g, cand_p);

    // ---------- stage 3: fp32 rescore of candidates (exact path) ----------
    {
        float* X96 = (float*)B0;
        float* H1  = (float*)B1;
        float* H2  = (float*)B2;
        float* H3  = (float*)B3;
        float* PFc = (float*)B4;
        float* T4  = (float*)B2;           // H2 dead by head time
        k_x96f<<<MC/256, 256, 0, stream>>>(coords, feats, times, ln_g, ln_b,
                                           sw1, sb1, sw2, sb2, cand_g, MC, X96);
        k_gemm<<<dim3( 4, MC/128), 256, 0, stream>>>(X96, mw1, mb1, H1, MC,  96, 256, 1);
        k_gemm<<<dim3( 8, MC/128), 256, 0, stream>>>(H1,  mw2, mb2, H2, MC, 256, 512, 1);
        k_gemm<<<dim3(12, MC/128), 256, 0, stream>>>(H2,  mw3, mb3, H3, MC, 512, 768, 1);
        k_gemm<<<dim3(12, MC/128), 256, 0, stream>>>(H3,  mw4, mb4, PFc, MC, 768, 768, 0);
        k_gemm<<<dim3( 6, MC/128), 256, 0, stream>>>(PFc, hw1, hb1, T4, MC, 768, 384, 1);
        k_score<<<MC/4, 256, 0, stream>>>(T4, hw2, hb2, fscores, MC);

        // ---------- stage 4: final top-128 per batch (bitonic) ----------
        k_fsel<<<NB, 256, 0, stream>>>(fscores, offs, cand_g, cand_p,
                                       coords, times, tok_src, out_cent, out_mask);
        k_tokens<<<(NB*MT*192)/256, 256, 0, stream>>>(PFc, tok_src, out_tok);
    }
}

// Round 15
// 1093.171 us; speedup vs baseline: 1.3225x; 1.3225x over previous
//
#include <hip/hip_runtime.h>
#include <cstdint>

#define NPTS 131072
#define NB 64
#define MAXPB 2560
#define MT 128
#define TD 768
#define CAND 160
#define MC (NB * CAND)   // 10240 candidate rows

typedef _Float16 f16;
typedef _Float16 f16x8 __attribute__((ext_vector_type(8)));
typedef float f32x4 __attribute__((ext_vector_type(4)));

__device__ __forceinline__ uint32_t pk2(float a, float b) {
    f16 ha = (f16)a, hb = (f16)b;
    return (uint32_t)__builtin_bit_cast(unsigned short, ha) |
           ((uint32_t)__builtin_bit_cast(unsigned short, hb) << 16);
}

// float -> order-preserving u32 (unsigned asc == float asc)
__device__ __forceinline__ uint32_t sortable(float f) {
    uint32_t u = __builtin_bit_cast(uint32_t, f);
    return u ^ (uint32_t)(((int32_t)u >> 31) | 0x80000000);
}

// direct HBM -> LDS, 16B per lane. LDS dest = wave-uniform base + lane*16.
__device__ __forceinline__ void gload16(const void* g, void* l) {
    __builtin_amdgcn_global_load_lds(
        (const __attribute__((address_space(1))) uint32_t*)g,
        (__attribute__((address_space(3))) uint32_t*)l,
        16, 0, 0);
}

// ---------------------------------------------------------------------------
// offsets via binary search on sorted batch_ids
// ---------------------------------------------------------------------------
__global__ void k_counts(const int* __restrict__ bids, int* __restrict__ offs)
{
    int b = threadIdx.x;
    if (b > NB) return;
    int lo = 0, hi = NPTS;
    while (lo < hi) { int mid = (lo + hi) >> 1; if (bids[mid] < b) lo = mid + 1; else hi = mid; }
    offs[b] = lo;
}

// ---------------------------------------------------------------------------
// weight cast: W[K][N] fp32 -> Wt[N][Kpad] f16 (zero-padded K)
// ---------------------------------------------------------------------------
__global__ __launch_bounds__(256) void k_cvtw(const float* __restrict__ W,
                                              unsigned short* __restrict__ out,
                                              int K, int N, int Kpad)
{
    int i = blockIdx.x * 256 + threadIdx.x;
    if (i >= N * Kpad) return;
    int n = i / Kpad, k = i % Kpad;
    f16 v = (f16)0.f;
    if (k < K) v = (f16)W[(size_t)k * N + n];
    out[i] = __builtin_bit_cast(unsigned short, v);
}

// fused head bias: bf[n] = hb1[n] + sum_j mb4[j] * hw1[j][n]   (n < 384)
__global__ void k_fuseb(const float* __restrict__ mb4, const float* __restrict__ hw1,
                        const float* __restrict__ hb1, float* __restrict__ bf)
{
    int n = blockIdx.x * 128 + threadIdx.x;
    if (n >= 384) return;
    float s = hb1[n];
    for (int j = 0; j < 768; ++j) s = fmaf(mb4[j], hw1[(size_t)j * 384 + n], s);
    bf[n] = s;
}

// ---------------------------------------------------------------------------
// Per-point front-end, f16 output [M][128] = [feat32, sp64, pad32].
// Also initializes scores[p] = hb2 (accumulated by fused L4' epilogue).
// ---------------------------------------------------------------------------
__global__ __launch_bounds__(256) void k_x96h(
    const float* __restrict__ coords, const float* __restrict__ feats,
    const float* __restrict__ times,
    const float* __restrict__ ln_g, const float* __restrict__ ln_b,
    const float* __restrict__ sw1, const float* __restrict__ sb1,
    const float* __restrict__ sw2, const float* __restrict__ sb2,
    const float* __restrict__ hb2, float* __restrict__ scores,
    int p0, int M, unsigned short* __restrict__ X)
{
    __shared__ float w1[256], w2[4096], b1[64], b2[64];
    int t = threadIdx.x;
    w1[t] = sw1[t];
    for (int i = t; i < 4096; i += 256) w2[i] = sw2[i];
    if (t < 64) { b1[t] = sb1[t]; b2[t] = sb2[t]; }
    __syncthreads();

    int r = blockIdx.x * 256 + t;
    if (r >= M) return;
    int p = p0 + r;
    scores[p] = hb2[0];
    unsigned short* out = X + (size_t)r * 128;

    float x0 = coords[(size_t)p*3+0], x1 = coords[(size_t)p*3+1];
    float x2 = coords[(size_t)p*3+2], x3 = times[p];
    float mu = 0.25f*(x0+x1+x2+x3);
    float d0 = x0-mu, d1 = x1-mu, d2 = x2-mu, d3 = x3-mu;
    float var = 0.25f*(d0*d0+d1*d1+d2*d2+d3*d3);
    float inv = 1.0f / sqrtf(var + 1e-5f);
    float xn0 = d0*inv*ln_g[0]+ln_b[0];
    float xn1 = d1*inv*ln_g[1]+ln_b[1];
    float xn2 = d2*inv*ln_g[2]+ln_b[2];
    float xn3 = d3*inv*ln_g[3]+ln_b[3];

    float s1[64];
    #pragma unroll
    for (int j = 0; j < 64; ++j) {
        float a = b1[j];
        a = fmaf(xn0, w1[j],       a);
        a = fmaf(xn1, w1[64 + j],  a);
        a = fmaf(xn2, w1[128 + j], a);
        a = fmaf(xn3, w1[192 + j], a);
        s1[j] = fmaxf(a, 0.f);
    }
    #pragma unroll
    for (int j = 0; j < 32; j += 8) {
        float4 f0 = *(const float4*)(feats + (size_t)p*32 + j);
        float4 f1 = *(const float4*)(feats + (size_t)p*32 + j + 4);
        uint4 u = make_uint4(pk2(f0.x,f0.y), pk2(f0.z,f0.w),
                             pk2(f1.x,f1.y), pk2(f1.z,f1.w));
        *(uint4*)(out + j) = u;
    }
    for (int j0 = 0; j0 < 64; j0 += 8) {
        float a[8];
        #pragma unroll
        for (int i = 0; i < 8; ++i) a[i] = b2[j0+i];
        #pragma unroll
        for (int k = 0; k < 64; ++k) {
            float s = s1[k];
            const float* wr = &w2[k*64 + j0];
            #pragma unroll
            for (int i = 0; i < 8; ++i) a[i] = fmaf(s, wr[i], a[i]);
        }
        #pragma unroll
        for (int i = 0; i < 8; ++i) a[i] = fmaxf(a[i], 0.f);
        uint4 u = make_uint4(pk2(a[0],a[1]), pk2(a[2],a[3]),
                             pk2(a[4],a[5]), pk2(a[6],a[7]));
        *(uint4*)(out + 32 + j0) = u;
    }
    uint4 z = make_uint4(0,0,0,0);
    *(uint4*)(out + 96)  = z;
    *(uint4*)(out + 104) = z;
    *(uint4*)(out + 112) = z;
    *(uint4*)(out + 120) = z;
}

// ---------------------------------------------------------------------------
// Per-point front-end, FP32 output, gather variant (rescore pass)
// ---------------------------------------------------------------------------
__global__ __launch_bounds__(256) void k_x96f(
    const float* __restrict__ coords, const float* __restrict__ feats,
    const float* __restrict__ times,
    const float* __restrict__ ln_g, const float* __restrict__ ln_b,
    const float* __restrict__ sw1, const float* __restrict__ sb1,
    const float* __restrict__ sw2, const float* __restrict__ sb2,
    const int* __restrict__ sel, int M, float* __restrict__ X96)
{
    __shared__ float w1[256], w2[4096], b1[64], b2[64];
    int t = threadIdx.x;
    w1[t] = sw1[t];
    for (int i = t; i < 4096; i += 256) w2[i] = sw2[i];
    if (t < 64) { b1[t] = sb1[t]; b2[t] = sb2[t]; }
    __syncthreads();

    int r = blockIdx.x * 256 + t;
    if (r >= M) return;
    int p = sel[r];
    float* out = X96 + (size_t)r * 96;
    if (p < 0) {
        for (int j = 0; j < 96; j += 4) *(float4*)(out + j) = make_float4(0.f,0.f,0.f,0.f);
        return;
    }
    float x0 = coords[(size_t)p*3+0], x1 = coords[(size_t)p*3+1];
    float x2 = coords[(size_t)p*3+2], x3 = times[p];
    float mu = 0.25f*(x0+x1+x2+x3);
    float d0 = x0-mu, d1 = x1-mu, d2 = x2-mu, d3 = x3-mu;
    float var = 0.25f*(d0*d0+d1*d1+d2*d2+d3*d3);
    float inv = 1.0f / sqrtf(var + 1e-5f);
    float xn0 = d0*inv*ln_g[0]+ln_b[0];
    float xn1 = d1*inv*ln_g[1]+ln_b[1];
    float xn2 = d2*inv*ln_g[2]+ln_b[2];
    float xn3 = d3*inv*ln_g[3]+ln_b[3];

    float s1[64];
    #pragma unroll
    for (int j = 0; j < 64; ++j) {
        float a = b1[j];
        a = fmaf(xn0, w1[j],       a);
        a = fmaf(xn1, w1[64 + j],  a);
        a = fmaf(xn2, w1[128 + j], a);
        a = fmaf(xn3, w1[192 + j], a);
        s1[j] = fmaxf(a, 0.f);
    }
    #pragma unroll
    for (int j = 0; j < 32; j += 4)
        *(float4*)(out + j) = *(const float4*)(feats + (size_t)p*32 + j);

    for (int j0 = 0; j0 < 64; j0 += 4) {
        float a0 = b2[j0+0], a1 = b2[j0+1], a2 = b2[j0+2], a3 = b2[j0+3];
        #pragma unroll
        for (int k = 0; k < 64; ++k) {
            float s = s1[k];
            const float* wr = &w2[k*64 + j0];
            a0 = fmaf(s, wr[0], a0);
            a1 = fmaf(s, wr[1], a1);
            a2 = fmaf(s, wr[2], a2);
            a3 = fmaf(s, wr[3], a3);
        }
        *(float4*)(out + 32 + j0) =
            make_float4(fmaxf(a0,0.f), fmaxf(a1,0.f), fmaxf(a2,0.f), fmaxf(a3,0.f));
    }
}

// ---------------------------------------------------------------------------
// Pure-f16 MFMA GEMM 128x128 (scoring): O = act(A @ Bt^T + b), f16 out.
// If scores != nullptr: fused head — no O writes; per row atomicAdd of
// sum_col relu(acc+b)*hw2[col] into scores[row].
// ---------------------------------------------------------------------------
__global__ __launch_bounds__(256, 3) void k_hgemm(
    const unsigned short* __restrict__ A, const unsigned short* __restrict__ Bt,
    const float* __restrict__ bias, unsigned short* __restrict__ O,
    const float* __restrict__ hw2, float* __restrict__ scores,
    int M, int K, int N, int relu)
{
    __shared__ unsigned short sA[128*64];
    __shared__ unsigned short sB[128*64];
    const int tid = threadIdx.x;
    const int bm = blockIdx.y, bn = blockIdx.x;
    const int lane = tid & 63, w = tid >> 6;
    const int wm = w >> 1, wn = w & 1;
    const int lr = lane & 15, lg = lane >> 4;

    const int srow = lane >> 3;                 // 0..7 == r&7 within chunk
    const int sblk = (lane & 7) ^ srow;         // pre-swizzled source block
    const unsigned short* ga0 = A  + ((size_t)(bm*128 + w*32 + srow)) * K + sblk*8;
    const unsigned short* gb0 = Bt + ((size_t)(bn*128 + w*32 + srow)) * K + sblk*8;

    f32x4 acc[4][4];
    #pragma unroll
    for (int m = 0; m < 4; ++m)
        #pragma unroll
        for (int n = 0; n < 4; ++n) acc[m][n] = (f32x4){0.f,0.f,0.f,0.f};

    for (int kt = 0; kt < K; kt += 64) {
        #pragma unroll
        for (int i = 0; i < 4; ++i) {
            gload16(ga0 + kt + (size_t)(i*8)*K, sA + (w*32 + i*8)*64);
            gload16(gb0 + kt + (size_t)(i*8)*K, sB + (w*32 + i*8)*64);
        }
        __syncthreads();

        #pragma unroll
        for (int kk = 0; kk < 64; kk += 32) {
            const int jj = lg + (kk >> 3);
            f16x8 af[4], bf[4];
            #pragma unroll
            for (int m = 0; m < 4; ++m) {
                int r = wm*64 + m*16 + lr;
                af[m] = *(const f16x8*)&sA[r*64 + ((jj ^ (r & 7)) << 3)];
            }
            #pragma unroll
            for (int n = 0; n < 4; ++n) {
                int r = wn*64 + n*16 + lr;
                bf[n] = *(const f16x8*)&sB[r*64 + ((jj ^ (r & 7)) << 3)];
            }
            #pragma unroll
            for (int m = 0; m < 4; ++m)
                #pragma unroll
                for (int n = 0; n < 4; ++n)
                    acc[m][n] = __builtin_amdgcn_mfma_f32_16x16x32_f16(af[m], bf[n], acc[m][n], 0, 0, 0);
        }
        __syncthreads();
    }

    if (scores) {
        float part[4][4];
        #pragma unroll
        for (int m = 0; m < 4; ++m)
            #pragma unroll
            for (int q = 0; q < 4; ++q) part[m][q] = 0.f;
        #pragma unroll
        for (int n = 0; n < 4; ++n) {
            int colg = bn*128 + wn*64 + n*16 + lr;
            float bb = bias[colg];
            float wv = hw2[colg];
            #pragma unroll
            for (int m = 0; m < 4; ++m)
                #pragma unroll
                for (int q = 0; q < 4; ++q) {
                    float v = fmaxf(acc[m][n][q] + bb, 0.f);
                    part[m][q] = fmaf(v, wv, part[m][q]);
                }
        }
        #pragma unroll
        for (int m = 0; m < 4; ++m)
            #pragma unroll
            for (int q = 0; q < 4; ++q) {
                float s = part[m][q];
                s += __shfl_xor(s, 1);
                s += __shfl_xor(s, 2);
                s += __shfl_xor(s, 4);
                s += __shfl_xor(s, 8);
                if (lr == 0)
                    atomicAdd(&scores[bm*128 + wm*64 + m*16 + lg*4 + q], s);
            }
        return;
    }

    #pragma unroll
    for (int n = 0; n < 4; ++n) {
        int col = bn*128 + wn*64 + n*16 + lr;
        float bb = bias[col];
        #pragma unroll
        for (int m = 0; m < 4; ++m) {
            int row0 = bm*128 + wm*64 + m*16 + lg*4;
            #pragma unroll
            for (int q = 0; q < 4; ++q) {
                float v = acc[m][n][q] + bb;
                if (relu) v = fmaxf(v, 0.f);
                f16 h = (f16)v;
                O[(size_t)(row0 + q) * N + col] = __builtin_bit_cast(unsigned short, h);
            }
        }
    }
}

// ---------------------------------------------------------------------------
// Pure-f16 MFMA GEMM 128x256 tile, 8 waves (2x4) — for N multiple of 256.
// ---------------------------------------------------------------------------
__global__ __launch_bounds__(512) void k_hgemm2(
    const unsigned short* __restrict__ A, const unsigned short* __restrict__ Bt,
    const float* __restrict__ bias, unsigned short* __restrict__ O,
    int M, int K, int N, int relu)
{
    __shared__ unsigned short sA[128*64];   // 16 KiB
    __shared__ unsigned short sB[256*64];   // 32 KiB
    const int tid = threadIdx.x;
    const int bm = blockIdx.y, bn = blockIdx.x;
    const int lane = tid & 63, w = tid >> 6;      // 8 waves
    const int wm = w >> 2, wn = w & 3;            // 2 x 4 wave grid
    const int lr = lane & 15, lg = lane >> 4;

    const int srow = lane >> 3;
    const int sblk = (lane & 7) ^ srow;

    const unsigned short* gsrc[6];
    unsigned short* ldst[6];
    #pragma unroll
    for (int i = 0; i < 6; ++i) {
        int c = w * 6 + i;                        // wave-uniform
        if (c < 16) {
            gsrc[i] = A + (size_t)(bm*128 + c*8 + srow) * K + sblk*8;
            ldst[i] = sA + c*8*64;
        } else {
            gsrc[i] = Bt + (size_t)(bn*256 + (c-16)*8 + srow) * K + sblk*8;
            ldst[i] = sB + (size_t)(c-16)*8*64;
        }
    }

    f32x4 acc[4][4];
    #pragma unroll
    for (int m = 0; m < 4; ++m)
        #pragma unroll
        for (int n = 0; n < 4; ++n) acc[m][n] = (f32x4){0.f,0.f,0.f,0.f};

    for (int kt = 0; kt < K; kt += 64) {
        #pragma unroll
        for (int i = 0; i < 6; ++i) gload16(gsrc[i] + kt, ldst[i]);
        __syncthreads();

        #pragma unroll
        for (int kk = 0; kk < 64; kk += 32) {
            const int jj = lg + (kk >> 3);
            f16x8 af[4], bf[4];
            #pragma unroll
            for (int m = 0; m < 4; ++m) {
                int r = wm*64 + m*16 + lr;
                af[m] = *(const f16x8*)&sA[r*64 + ((jj ^ (r & 7)) << 3)];
            }
            #pragma unroll
            for (int n = 0; n < 4; ++n) {
                int r = wn*64 + n*16 + lr;
                bf[n] = *(const f16x8*)&sB[r*64 + ((jj ^ (r & 7)) << 3)];
            }
            #pragma unroll
            for (int m = 0; m < 4; ++m)
                #pragma unroll
                for (int n = 0; n < 4; ++n)
                    acc[m][n] = __builtin_amdgcn_mfma_f32_16x16x32_f16(af[m], bf[n], acc[m][n], 0, 0, 0);
        }
        __syncthreads();
    }

    #pragma unroll
    for (int n = 0; n < 4; ++n) {
        int col = bn*256 + wn*64 + n*16 + lr;
        float bb = bias[col];
        #pragma unroll
        for (int m = 0; m < 4; ++m) {
            int row0 = bm*128 + wm*64 + m*16 + lg*4;
            #pragma unroll
            for (int q = 0; q < 4; ++q) {
                float v = acc[m][n][q] + bb;
                if (relu) v = fmaxf(v, 0.f);
                f16 h = (f16)v;
                O[(size_t)(row0 + q) * N + col] = __builtin_bit_cast(unsigned short, h);
            }
        }
    }
}

// ---------------------------------------------------------------------------
// fp32 GEMM: BM=128 x BN=64 x BK=32, 4x8/thread. (round-13 proven form)
// ---------------------------------------------------------------------------
#define BM 128
#define BN 64
#define BK 32

__global__ __launch_bounds__(256, 4) void k_gemm(
    const float* __restrict__ A, const float* __restrict__ W,
    const float* __restrict__ bias, float* __restrict__ C,
    int M, int K, int Nn, int relu)
{
    __shared__ float As[BK][BM + 4];   // 16.9 KiB
    __shared__ float Bs[BK][BN];       //  8.2 KiB
    const int tid = threadIdx.x;
    const int bm = blockIdx.y, bn = blockIdx.x;
    const int tr = tid >> 3, tc = tid & 7;           // 32x8 threads, 4x8 each
    const int ar0 = tid >> 1, ac0 = (tid & 1) * 16;  // A-stage: 1 row x 4 float4
    const int bk0 = tid >> 3, bn0 = (tid & 7) * 8;   // B-stage: 1 row x 2 float4
    const float* Ab = A + (size_t)bm * BM * K;
    const float* Wb = W + (size_t)bn * BN;

    float acc[4][8];
    #pragma unroll
    for (int i = 0; i < 4; ++i)
        #pragma unroll
        for (int j = 0; j < 8; ++j) acc[i][j] = 0.f;

    for (int k0 = 0; k0 < K; k0 += BK) {
        float4 a0 = *(const float4*)(Ab + (size_t)ar0*K + k0 + ac0);
        float4 a1 = *(const float4*)(Ab + (size_t)ar0*K + k0 + ac0 + 4);
        float4 a2 = *(const float4*)(Ab + (size_t)ar0*K + k0 + ac0 + 8);
        float4 a3 = *(const float4*)(Ab + (size_t)ar0*K + k0 + ac0 + 12);
        float4 w0 = *(const float4*)(Wb + (size_t)(k0+bk0)*Nn + bn0);
        float4 w1 = *(const float4*)(Wb + (size_t)(k0+bk0)*Nn + bn0 + 4);
        As[ac0+ 0][ar0] = a0.x; As[ac0+ 1][ar0] = a0.y;
        As[ac0+ 2][ar0] = a0.z; As[ac0+ 3][ar0] = a0.w;
        As[ac0+ 4][ar0] = a1.x; As[ac0+ 5][ar0] = a1.y;
        As[ac0+ 6][ar0] = a1.z; As[ac0+ 7][ar0] = a1.w;
        As[ac0+ 8][ar0] = a2.x; As[ac0+ 9][ar0] = a2.y;
        As[ac0+10][ar0] = a2.z; As[ac0+11][ar0] = a2.w;
        As[ac0+12][ar0] = a3.x; As[ac0+13][ar0] = a3.y;
        As[ac0+14][ar0] = a3.z; As[ac0+15][ar0] = a3.w;
        *(float4*)&Bs[bk0][bn0]     = w0;
        *(float4*)&Bs[bk0][bn0 + 4] = w1;
        __syncthreads();
        #pragma unroll
        for (int kk = 0; kk < BK; ++kk) {
            float4 av  = *(const float4*)&As[kk][tr*4];
            float4 bv0 = *(const float4*)&Bs[kk][tc*8];
            float4 bv1 = *(const float4*)&Bs[kk][tc*8+4];
            float a[4] = {av.x, av.y, av.z, av.w};
            float b[8] = {bv0.x,bv0.y,bv0.z,bv0.w, bv1.x,bv1.y,bv1.z,bv1.w};
            #pragma unroll
            for (int i = 0; i < 4; ++i)
                #pragma unroll
                for (int j = 0; j < 8; ++j)
                    acc[i][j] = fmaf(a[i], b[j], acc[i][j]);
        }
        __syncthreads();
    }

    float bl[8];
    #pragma unroll
    for (int j = 0; j < 8; ++j) bl[j] = bias[(size_t)bn*BN + tc*8 + j];
    #pragma unroll
    for (int i = 0; i < 4; ++i) {
        int row = bm*BM + tr*4 + i;
        float v[8];
        #pragma unroll
        for (int j = 0; j < 8; ++j) {
            float x = acc[i][j] + bl[j];
            v[j] = relu ? fmaxf(x, 0.f) : x;
        }
        float* cr = C + (size_t)row*Nn + bn*BN + tc*8;
        *(float4*)(cr)     = make_float4(v[0],v[1],v[2],v[3]);
        *(float4*)(cr + 4) = make_float4(v[4],v[5],v[6],v[7]);
    }
}

// ---------------------------------------------------------------------------
// score from fp32 T4 (rescore path)
// ---------------------------------------------------------------------------
__global__ __launch_bounds__(256) void k_score(
    const float* __restrict__ T4, const float* __restrict__ hw2,
    const float* __restrict__ hb2, float* __restrict__ scores, int M)
{
    int wv = (blockIdx.x * 256 + threadIdx.x) >> 6;
    int lane = threadIdx.x & 63;
    if (wv >= M) return;
    const float* row = T4 + (size_t)wv * 384;
    float s = 0.f;
    #pragma unroll
    for (int j = 0; j < 384; j += 64) s = fmaf(row[j + lane], hw2[j + lane], s);
    for (int o = 32; o > 0; o >>= 1) s += __shfl_down(s, o, 64);
    if (lane == 0) scores[wv] = s + hb2[0];
}

// ---------------------------------------------------------------------------
// Stage 1 select: per-batch top-CAND via bitonic sort, 1024 threads.
// ---------------------------------------------------------------------------
#define TPAD 4096
__global__ __launch_bounds__(1024) void k_topcand(
    const float* __restrict__ scores, const int* __restrict__ offs,
    int* __restrict__ cand_g, int* __restrict__ cand_p)
{
    __shared__ uint64_t key[TPAD];   // 32 KiB
    int b = blockIdx.x, t = threadIdx.x;
    int off = offs[b];
    int cnt = min(offs[b+1] - off, MAXPB);

    for (int i = t; i < TPAD; i += 1024) {
        uint64_t k = 0;
        if (i < cnt)
            k = ((uint64_t)sortable(scores[off + i]) << 32) | (uint32_t)(~i);
        key[i] = k;
    }

    for (int ksz = 2; ksz <= TPAD; ksz <<= 1) {
        for (int j = ksz >> 1; j > 0; j >>= 1) {
            __syncthreads();
            #pragma unroll 2
            for (int i = t; i < TPAD; i += 1024) {
                int ix = i ^ j;
                if (ix > i) {
                    uint64_t a = key[i], c = key[ix];
                    bool up = (i & ksz) == 0;
                    if (up ? (a < c) : (a > c)) { key[i] = c; key[ix] = a; }
                }
            }
        }
    }
    __syncthreads();

    if (t < CAND) {
        if (t < cnt) {
            int pos = (int)(~(uint32_t)key[t]);
            cand_g[b*CAND + t] = off + pos;
            cand_p[b*CAND + t] = pos;
        } else {
            cand_g[b*CAND + t] = -1;
            cand_p[b*CAND + t] = MAXPB + t;
        }
    }
}

// ---------------------------------------------------------------------------
// Stage 2: final top-MT by fp32 score via bitonic.
// ---------------------------------------------------------------------------
__global__ __launch_bounds__(256) void k_fsel(
    const float* __restrict__ fscores, const int* __restrict__ offs,
    const int* __restrict__ cand_g, const int* __restrict__ cand_p,
    const float* __restrict__ coords, const float* __restrict__ times,
    int* __restrict__ tok_src, float* __restrict__ out_cent,
    float* __restrict__ out_mask)
{
    __shared__ uint64_t key[256];
    int b = blockIdx.x, t = threadIdx.x;
    int cnt = min(offs[b+1] - offs[b], MAXPB);
    int cntc = min(cnt, CAND);

    uint64_t k = 0;
    if (t < cntc) {
        uint32_t s32 = sortable(fscores[b*CAND + t]);
        uint32_t pos = (uint32_t)cand_p[b*CAND + t];
        k = ((uint64_t)s32 << 32) | (((~pos) & 0xFFFu) << 8) | (uint32_t)t;
    }
    key[t] = k;

    for (int ksz = 2; ksz <= 256; ksz <<= 1) {
        for (int j = ksz >> 1; j > 0; j >>= 1) {
            __syncthreads();
            int ix = t ^ j;
            if (ix > t) {
                uint64_t a = key[t], c = key[ix];
                bool up = (t & ksz) == 0;
                if (up ? (a < c) : (a > c)) { key[t] = c; key[ix] = a; }
            }
        }
    }
    __syncthreads();

    if (t < MT) {
        if (t < cntc) {
            int j = (int)(key[t] & 0xFF);
            int row = b*CAND + j;
            int g = cand_g[row];
            tok_src[b*MT + t] = row;
            out_mask[b*MT + t] = 1.0f;
            *(float4*)&out_cent[(size_t)(b*MT + t) * 4] =
                make_float4(coords[(size_t)g*3+0], coords[(size_t)g*3+1],
                            coords[(size_t)g*3+2], times[g]);
        } else {
            tok_src[b*MT + t] = -1;
            out_mask[b*MT + t] = 0.0f;
            *(float4*)&out_cent[(size_t)(b*MT + t) * 4] = make_float4(0.f,0.f,0.f,0.f);
        }
    }
}

// gather tokens from candidate point_feats
__global__ __launch_bounds__(256) void k_tokens(const float* __restrict__ PFc,
                                                const int* __restrict__ tok_src,
                                                float* __restrict__ out)
{
    int i = blockIdx.x * 256 + threadIdx.x;   // 8192*192 float4
    int row = i / 192, c = i % 192;
    int src = tok_src[row];
    float4 v = make_float4(0.f,0.f,0.f,0.f);
    if (src >= 0) v = ((const float4*)PFc)[(size_t)src*192 + c];
    ((float4*)out)[(size_t)row*192 + c] = v;
}

// ---------------------------------------------------------------------------
extern "C" void kernel_launch(void* const* d_in, const int* in_sizes, int n_in,
                              void* d_out, int out_size, void* d_ws, size_t ws_size,
                              hipStream_t stream)
{
    const float* coords = (const float*)d_in[0];
    const float* feats  = (const float*)d_in[1];
    const float* times  = (const float*)d_in[2];
    const int*   bids   = (const int*)  d_in[3];
    const float* ln_g = (const float*)d_in[4];
    const float* ln_b = (const float*)d_in[5];
    const float* sw1  = (const float*)d_in[6];
    const float* sb1  = (const float*)d_in[7];
    const float* sw2  = (const float*)d_in[8];
    const float* sb2  = (const float*)d_in[9];
    const float* mw1  = (const float*)d_in[10];
    const float* mb1  = (const float*)d_in[11];
    const float* mw2  = (const float*)d_in[12];
    const float* mb2  = (const float*)d_in[13];
    const float* mw3  = (const float*)d_in[14];
    const float* mb3  = (const float*)d_in[15];
    const float* mw4  = (const float*)d_in[16];
    const float* mb4  = (const float*)d_in[17];
    const float* hw1  = (const float*)d_in[18];
    const float* hb1  = (const float*)d_in[19];
    const float* hw2  = (const float*)d_in[20];
    const float* hb2  = (const float*)d_in[21];

    float* out_tok  = (float*)d_out;
    float* out_cent = out_tok + (size_t)NB*MT*TD;
    float* out_mask = out_cent + (size_t)NB*MT*4;

    char* wsb = (char*)d_ws;
    size_t off = 0;
    auto alloc = [&](size_t bytes) {
        char* p = wsb + off;
        off = (off + bytes + 255) & ~(size_t)255;
        return p;
    };
    auto mx = [](size_t a, size_t b) { return a > b ? a : b; };

    int*   offs    = (int*)  alloc((NB + 1) * 4);
    float* scores  = (float*)alloc((size_t)NPTS * 4);
    float* fscores = (float*)alloc((size_t)MC * 4);
    int*   cand_g  = (int*)  alloc((size_t)MC * 4);
    int*   cand_p  = (int*)  alloc((size_t)MC * 4);
    int*   tok_src = (int*)  alloc((size_t)NB * MT * 4);
    unsigned short* wt1h = (unsigned short*)alloc((size_t)256 * 128 * 2);
    unsigned short* wt2h = (unsigned short*)alloc((size_t)512 * 256 * 2);
    unsigned short* wt3h = (unsigned short*)alloc((size_t)768 * 512 * 2);
    float* zero384 = (float*)alloc(384 * 4);
    float* wfused  = (float*)alloc((size_t)768 * 384 * 4);   // W' = mw4@hw1 (fp32)
    float* bfused  = (float*)alloc(384 * 4);                 // b' = mb4@hw1 + hb1
    unsigned short* wfh = (unsigned short*)alloc((size_t)384 * 768 * 2);  // W'^T f16
    size_t base = off;

    int Nc = 8192;
    const int cands[3] = {32768, 16384, 8192};
    for (int ci = 0; ci < 3; ++ci) {
        size_t n = cands[ci];
        size_t need = base
            + mx(n*128*2, (size_t)MC*96*4)
            + mx(n*256*2, (size_t)MC*256*4)
            + mx(n*512*2, (size_t)MC*512*4)
            + 2 * mx(n*768*2, (size_t)MC*768*4)
            + 6*256;
        if (need <= ws_size) { Nc = (int)n; break; }
    }
    char* B0 = alloc(mx((size_t)Nc*128*2, (size_t)MC*96*4));
    char* B1 = alloc(mx((size_t)Nc*256*2, (size_t)MC*256*4));
    char* B2 = alloc(mx((size_t)Nc*512*2, (size_t)MC*512*4));
    char* B3 = alloc(mx((size_t)Nc*768*2, (size_t)MC*768*4));
    char* B4 = alloc(mx((size_t)Nc*768*2, (size_t)MC*768*4));

    // ---------- setup ----------
    k_counts<<<1, 128, 0, stream>>>(bids, offs);
    k_cvtw<<<(256*128+255)/256, 256, 0, stream>>>(mw1, wt1h,  96, 256, 128);
    k_cvtw<<<(512*256+255)/256, 256, 0, stream>>>(mw2, wt2h, 256, 512, 256);
    k_cvtw<<<(768*512+255)/256, 256, 0, stream>>>(mw3, wt3h, 512, 768, 512);
    // fused head: W' = mw4 @ hw1 (768x384), b' = mb4 @ hw1 + hb1
    hipMemsetAsync(zero384, 0, 384 * 4, stream);
    k_gemm<<<dim3(6, 6), 256, 0, stream>>>(mw4, hw1, zero384, wfused, 768, 768, 384, 0);
    k_fuseb<<<3, 128, 0, stream>>>(mb4, hw1, hb1, bfused);
    k_cvtw<<<(384*768+255)/256, 256, 0, stream>>>(wfused, wfh, 768, 384, 768);

    // ---------- stage 1: pure-f16 MFMA scoring (mw4+hw1 folded, fused head) --
    {
        unsigned short* X   = (unsigned short*)B0;   // [Nc][128]
        unsigned short* H1h = (unsigned short*)B1;   // [Nc][256]
        unsigned short* H2h = (unsigned short*)B2;   // [Nc][512]
        unsigned short* H3h = (unsigned short*)B3;   // [Nc][768]
        for (int p0 = 0; p0 < NPTS; p0 += Nc) {
            int Mi = min(Nc, NPTS - p0);
            k_x96h<<<(Mi+255)/256, 256, 0, stream>>>(coords, feats, times, ln_g, ln_b,
                                                     sw1, sb1, sw2, sb2, hb2,
                                                     scores, p0, Mi, X);
            k_hgemm <<<dim3(2, Mi/128), 256, 0, stream>>>(X,   wt1h, mb1, H1h,
                                                          nullptr, nullptr, Mi, 128, 256, 1);
            k_hgemm2<<<dim3(2, Mi/128), 512, 0, stream>>>(H1h, wt2h, mb2, H2h, Mi, 256, 512, 1);
            k_hgemm2<<<dim3(3, Mi/128), 512, 0, stream>>>(H2h, wt3h, mb3, H3h, Mi, 512, 768, 1);
            k_hgemm <<<dim3(3, Mi/128), 256, 0, stream>>>(H3h, wfh,  bfused, nullptr,
                                                          hw2, scores + p0, Mi, 768, 384, 1);
        }
    }

    // ---------- stage 2: capture top-CAND per batch (bitonic, 1024 thr) ------
    k_topcand<<<NB, 1024, 0, stream>>>(scores, offs, cand_g, cand_p);

    // ---------- stage 3: fp32 rescore of candidates (exact path) ----------
    {
        float* X96 = (float*)B0;
        float* H1  = (float*)B1;
        float* H2  = (float*)B2;
        float* H3  = (float*)B3;
        float* PFc = (float*)B4;
        float* T4  = (float*)B2;           // H2 dead by head time
        k_x96f<<<MC/256, 256, 0, stream>>>(coords, feats, times, ln_g, ln_b,
                                           sw1, sb1, sw2, sb2, cand_g, MC, X96);
        k_gemm<<<dim3( 4, MC/128), 256, 0, stream>>>(X96, mw1, mb1, H1, MC,  96, 256, 1);
        k_gemm<<<dim3( 8, MC/128), 256, 0, stream>>>(H1,  mw2, mb2, H2, MC, 256, 512, 1);
        k_gemm<<<dim3(12, MC/128), 256, 0, stream>>>(H2,  mw3, mb3, H3, MC, 512, 768, 1);
        k_gemm<<<dim3(12, MC/128), 256, 0, stream>>>(H3,  mw4, mb4, PFc, MC, 768, 768, 0);
        k_gemm<<<dim3( 6, MC/128), 256, 0, stream>>>(PFc, hw1, hb1, T4, MC, 768, 384, 1);
        k_score<<<MC/4, 256, 0, stream>>>(T4, hw2, hb2, fscores, MC);

        // ---------- stage 4: final top-128 per batch (bitonic) ----------
        k_fsel<<<NB, 256, 0, stream>>>(fscores, offs, cand_g, cand_p,
                                       coords, times, tok_src, out_cent, out_mask);
        k_tokens<<<(NB*MT*192)/256, 256, 0, stream>>>(PFc, tok_src, out_tok);
    }
}

// Round 16
// 1082.075 us; speedup vs baseline: 1.3361x; 1.0103x over previous
//
#include <hip/hip_runtime.h>
#include <cstdint>

#define NPTS 131072
#define NB 64
#define MAXPB 2560
#define MT 128
#define TD 768
#define CAND 144
#define MC (NB * CAND)   // 9216 candidate rows

typedef _Float16 f16;
typedef _Float16 f16x8 __attribute__((ext_vector_type(8)));
typedef float f32x4 __attribute__((ext_vector_type(4)));

__device__ __forceinline__ uint32_t pk2(float a, float b) {
    f16 ha = (f16)a, hb = (f16)b;
    return (uint32_t)__builtin_bit_cast(unsigned short, ha) |
           ((uint32_t)__builtin_bit_cast(unsigned short, hb) << 16);
}

// float -> order-preserving u32 (unsigned asc == float asc)
__device__ __forceinline__ uint32_t sortable(float f) {
    uint32_t u = __builtin_bit_cast(uint32_t, f);
    return u ^ (uint32_t)(((int32_t)u >> 31) | 0x80000000);
}

// direct HBM -> LDS, 16B per lane. LDS dest = wave-uniform base + lane*16.
__device__ __forceinline__ void gload16(const void* g, void* l) {
    __builtin_amdgcn_global_load_lds(
        (const __attribute__((address_space(1))) uint32_t*)g,
        (__attribute__((address_space(3))) uint32_t*)l,
        16, 0, 0);
}

// ---------------------------------------------------------------------------
// offsets via binary search on sorted batch_ids
// ---------------------------------------------------------------------------
__global__ void k_counts(const int* __restrict__ bids, int* __restrict__ offs)
{
    int b = threadIdx.x;
    if (b > NB) return;
    int lo = 0, hi = NPTS;
    while (lo < hi) { int mid = (lo + hi) >> 1; if (bids[mid] < b) lo = mid + 1; else hi = mid; }
    offs[b] = lo;
}

// ---------------------------------------------------------------------------
// weight cast: W[K][N] fp32 -> Wt[N][Kpad] f16 (zero-padded K)
// ---------------------------------------------------------------------------
__global__ __launch_bounds__(256) void k_cvtw(const float* __restrict__ W,
                                              unsigned short* __restrict__ out,
                                              int K, int N, int Kpad)
{
    int i = blockIdx.x * 256 + threadIdx.x;
    if (i >= N * Kpad) return;
    int n = i / Kpad, k = i % Kpad;
    f16 v = (f16)0.f;
    if (k < K) v = (f16)W[(size_t)k * N + n];
    out[i] = __builtin_bit_cast(unsigned short, v);
}

// fused head bias: bf[n] = hb1[n] + sum_j mb4[j] * hw1[j][n]   (n < 384)
__global__ void k_fuseb(const float* __restrict__ mb4, const float* __restrict__ hw1,
                        const float* __restrict__ hb1, float* __restrict__ bf)
{
    int n = blockIdx.x * 128 + threadIdx.x;
    if (n >= 384) return;
    float s = hb1[n];
    for (int j = 0; j < 768; ++j) s = fmaf(mb4[j], hw1[(size_t)j * 384 + n], s);
    bf[n] = s;
}

// ---------------------------------------------------------------------------
// Per-point front-end, f16 output [M][128] = [feat32, sp64, pad32].
// Also initializes scores[p] = hb2 (accumulated by fused L4' epilogue).
// ---------------------------------------------------------------------------
__global__ __launch_bounds__(256) void k_x96h(
    const float* __restrict__ coords, const float* __restrict__ feats,
    const float* __restrict__ times,
    const float* __restrict__ ln_g, const float* __restrict__ ln_b,
    const float* __restrict__ sw1, const float* __restrict__ sb1,
    const float* __restrict__ sw2, const float* __restrict__ sb2,
    const float* __restrict__ hb2, float* __restrict__ scores,
    int p0, int M, unsigned short* __restrict__ X)
{
    __shared__ float w1[256], w2[4096], b1[64], b2[64];
    int t = threadIdx.x;
    w1[t] = sw1[t];
    for (int i = t; i < 4096; i += 256) w2[i] = sw2[i];
    if (t < 64) { b1[t] = sb1[t]; b2[t] = sb2[t]; }
    __syncthreads();

    int r = blockIdx.x * 256 + t;
    if (r >= M) return;
    int p = p0 + r;
    scores[p] = hb2[0];
    unsigned short* out = X + (size_t)r * 128;

    float x0 = coords[(size_t)p*3+0], x1 = coords[(size_t)p*3+1];
    float x2 = coords[(size_t)p*3+2], x3 = times[p];
    float mu = 0.25f*(x0+x1+x2+x3);
    float d0 = x0-mu, d1 = x1-mu, d2 = x2-mu, d3 = x3-mu;
    float var = 0.25f*(d0*d0+d1*d1+d2*d2+d3*d3);
    float inv = 1.0f / sqrtf(var + 1e-5f);
    float xn0 = d0*inv*ln_g[0]+ln_b[0];
    float xn1 = d1*inv*ln_g[1]+ln_b[1];
    float xn2 = d2*inv*ln_g[2]+ln_b[2];
    float xn3 = d3*inv*ln_g[3]+ln_b[3];

    float s1[64];
    #pragma unroll
    for (int j = 0; j < 64; ++j) {
        float a = b1[j];
        a = fmaf(xn0, w1[j],       a);
        a = fmaf(xn1, w1[64 + j],  a);
        a = fmaf(xn2, w1[128 + j], a);
        a = fmaf(xn3, w1[192 + j], a);
        s1[j] = fmaxf(a, 0.f);
    }
    #pragma unroll
    for (int j = 0; j < 32; j += 8) {
        float4 f0 = *(const float4*)(feats + (size_t)p*32 + j);
        float4 f1 = *(const float4*)(feats + (size_t)p*32 + j + 4);
        uint4 u = make_uint4(pk2(f0.x,f0.y), pk2(f0.z,f0.w),
                             pk2(f1.x,f1.y), pk2(f1.z,f1.w));
        *(uint4*)(out + j) = u;
    }
    for (int j0 = 0; j0 < 64; j0 += 8) {
        float a[8];
        #pragma unroll
        for (int i = 0; i < 8; ++i) a[i] = b2[j0+i];
        #pragma unroll
        for (int k = 0; k < 64; ++k) {
            float s = s1[k];
            const float* wr = &w2[k*64 + j0];
            #pragma unroll
            for (int i = 0; i < 8; ++i) a[i] = fmaf(s, wr[i], a[i]);
        }
        #pragma unroll
        for (int i = 0; i < 8; ++i) a[i] = fmaxf(a[i], 0.f);
        uint4 u = make_uint4(pk2(a[0],a[1]), pk2(a[2],a[3]),
                             pk2(a[4],a[5]), pk2(a[6],a[7]));
        *(uint4*)(out + 32 + j0) = u;
    }
    uint4 z = make_uint4(0,0,0,0);
    *(uint4*)(out + 96)  = z;
    *(uint4*)(out + 104) = z;
    *(uint4*)(out + 112) = z;
    *(uint4*)(out + 120) = z;
}

// ---------------------------------------------------------------------------
// Per-point front-end, FP32 output, gather variant (rescore pass)
// ---------------------------------------------------------------------------
__global__ __launch_bounds__(256) void k_x96f(
    const float* __restrict__ coords, const float* __restrict__ feats,
    const float* __restrict__ times,
    const float* __restrict__ ln_g, const float* __restrict__ ln_b,
    const float* __restrict__ sw1, const float* __restrict__ sb1,
    const float* __restrict__ sw2, const float* __restrict__ sb2,
    const int* __restrict__ sel, int M, float* __restrict__ X96)
{
    __shared__ float w1[256], w2[4096], b1[64], b2[64];
    int t = threadIdx.x;
    w1[t] = sw1[t];
    for (int i = t; i < 4096; i += 256) w2[i] = sw2[i];
    if (t < 64) { b1[t] = sb1[t]; b2[t] = sb2[t]; }
    __syncthreads();

    int r = blockIdx.x * 256 + t;
    if (r >= M) return;
    int p = sel[r];
    float* out = X96 + (size_t)r * 96;
    if (p < 0) {
        for (int j = 0; j < 96; j += 4) *(float4*)(out + j) = make_float4(0.f,0.f,0.f,0.f);
        return;
    }
    float x0 = coords[(size_t)p*3+0], x1 = coords[(size_t)p*3+1];
    float x2 = coords[(size_t)p*3+2], x3 = times[p];
    float mu = 0.25f*(x0+x1+x2+x3);
    float d0 = x0-mu, d1 = x1-mu, d2 = x2-mu, d3 = x3-mu;
    float var = 0.25f*(d0*d0+d1*d1+d2*d2+d3*d3);
    float inv = 1.0f / sqrtf(var + 1e-5f);
    float xn0 = d0*inv*ln_g[0]+ln_b[0];
    float xn1 = d1*inv*ln_g[1]+ln_b[1];
    float xn2 = d2*inv*ln_g[2]+ln_b[2];
    float xn3 = d3*inv*ln_g[3]+ln_b[3];

    float s1[64];
    #pragma unroll
    for (int j = 0; j < 64; ++j) {
        float a = b1[j];
        a = fmaf(xn0, w1[j],       a);
        a = fmaf(xn1, w1[64 + j],  a);
        a = fmaf(xn2, w1[128 + j], a);
        a = fmaf(xn3, w1[192 + j], a);
        s1[j] = fmaxf(a, 0.f);
    }
    #pragma unroll
    for (int j = 0; j < 32; j += 4)
        *(float4*)(out + j) = *(const float4*)(feats + (size_t)p*32 + j);

    for (int j0 = 0; j0 < 64; j0 += 4) {
        float a0 = b2[j0+0], a1 = b2[j0+1], a2 = b2[j0+2], a3 = b2[j0+3];
        #pragma unroll
        for (int k = 0; k < 64; ++k) {
            float s = s1[k];
            const float* wr = &w2[k*64 + j0];
            a0 = fmaf(s, wr[0], a0);
            a1 = fmaf(s, wr[1], a1);
            a2 = fmaf(s, wr[2], a2);
            a3 = fmaf(s, wr[3], a3);
        }
        *(float4*)(out + 32 + j0) =
            make_float4(fmaxf(a0,0.f), fmaxf(a1,0.f), fmaxf(a2,0.f), fmaxf(a3,0.f));
    }
}

// ---------------------------------------------------------------------------
// Pure-f16 MFMA GEMM 128x128 (scoring): O = act(A @ Bt^T + b), f16 out.
// If scores != nullptr: fused head — no O writes; per row atomicAdd of
// sum_col relu(acc+b)*hw2[col] into scores[row].
// ---------------------------------------------------------------------------
__global__ __launch_bounds__(256, 3) void k_hgemm(
    const unsigned short* __restrict__ A, const unsigned short* __restrict__ Bt,
    const float* __restrict__ bias, unsigned short* __restrict__ O,
    const float* __restrict__ hw2, float* __restrict__ scores,
    int M, int K, int N, int relu)
{
    __shared__ unsigned short sA[128*64];
    __shared__ unsigned short sB[128*64];
    const int tid = threadIdx.x;
    const int bm = blockIdx.y, bn = blockIdx.x;
    const int lane = tid & 63, w = tid >> 6;
    const int wm = w >> 1, wn = w & 1;
    const int lr = lane & 15, lg = lane >> 4;

    const int srow = lane >> 3;                 // 0..7 == r&7 within chunk
    const int sblk = (lane & 7) ^ srow;         // pre-swizzled source block
    const unsigned short* ga0 = A  + ((size_t)(bm*128 + w*32 + srow)) * K + sblk*8;
    const unsigned short* gb0 = Bt + ((size_t)(bn*128 + w*32 + srow)) * K + sblk*8;

    f32x4 acc[4][4];
    #pragma unroll
    for (int m = 0; m < 4; ++m)
        #pragma unroll
        for (int n = 0; n < 4; ++n) acc[m][n] = (f32x4){0.f,0.f,0.f,0.f};

    for (int kt = 0; kt < K; kt += 64) {
        #pragma unroll
        for (int i = 0; i < 4; ++i) {
            gload16(ga0 + kt + (size_t)(i*8)*K, sA + (w*32 + i*8)*64);
            gload16(gb0 + kt + (size_t)(i*8)*K, sB + (w*32 + i*8)*64);
        }
        __syncthreads();

        #pragma unroll
        for (int kk = 0; kk < 64; kk += 32) {
            const int jj = lg + (kk >> 3);
            f16x8 af[4], bf[4];
            #pragma unroll
            for (int m = 0; m < 4; ++m) {
                int r = wm*64 + m*16 + lr;
                af[m] = *(const f16x8*)&sA[r*64 + ((jj ^ (r & 7)) << 3)];
            }
            #pragma unroll
            for (int n = 0; n < 4; ++n) {
                int r = wn*64 + n*16 + lr;
                bf[n] = *(const f16x8*)&sB[r*64 + ((jj ^ (r & 7)) << 3)];
            }
            #pragma unroll
            for (int m = 0; m < 4; ++m)
                #pragma unroll
                for (int n = 0; n < 4; ++n)
                    acc[m][n] = __builtin_amdgcn_mfma_f32_16x16x32_f16(af[m], bf[n], acc[m][n], 0, 0, 0);
        }
        __syncthreads();
    }

    if (scores) {
        float part[4][4];
        #pragma unroll
        for (int m = 0; m < 4; ++m)
            #pragma unroll
            for (int q = 0; q < 4; ++q) part[m][q] = 0.f;
        #pragma unroll
        for (int n = 0; n < 4; ++n) {
            int colg = bn*128 + wn*64 + n*16 + lr;
            float bb = bias[colg];
            float wv = hw2[colg];
            #pragma unroll
            for (int m = 0; m < 4; ++m)
                #pragma unroll
                for (int q = 0; q < 4; ++q) {
                    float v = fmaxf(acc[m][n][q] + bb, 0.f);
                    part[m][q] = fmaf(v, wv, part[m][q]);
                }
        }
        #pragma unroll
        for (int m = 0; m < 4; ++m)
            #pragma unroll
            for (int q = 0; q < 4; ++q) {
                float s = part[m][q];
                s += __shfl_xor(s, 1);
                s += __shfl_xor(s, 2);
                s += __shfl_xor(s, 4);
                s += __shfl_xor(s, 8);
                if (lr == 0)
                    atomicAdd(&scores[bm*128 + wm*64 + m*16 + lg*4 + q], s);
            }
        return;
    }

    #pragma unroll
    for (int n = 0; n < 4; ++n) {
        int col = bn*128 + wn*64 + n*16 + lr;
        float bb = bias[col];
        #pragma unroll
        for (int m = 0; m < 4; ++m) {
            int row0 = bm*128 + wm*64 + m*16 + lg*4;
            #pragma unroll
            for (int q = 0; q < 4; ++q) {
                float v = acc[m][n][q] + bb;
                if (relu) v = fmaxf(v, 0.f);
                f16 h = (f16)v;
                O[(size_t)(row0 + q) * N + col] = __builtin_bit_cast(unsigned short, h);
            }
        }
    }
}

// ---------------------------------------------------------------------------
// Pure-f16 MFMA GEMM 128x256 tile, 8 waves (2x4) — for N multiple of 256.
// ---------------------------------------------------------------------------
__global__ __launch_bounds__(512) void k_hgemm2(
    const unsigned short* __restrict__ A, const unsigned short* __restrict__ Bt,
    const float* __restrict__ bias, unsigned short* __restrict__ O,
    int M, int K, int N, int relu)
{
    __shared__ unsigned short sA[128*64];   // 16 KiB
    __shared__ unsigned short sB[256*64];   // 32 KiB
    const int tid = threadIdx.x;
    const int bm = blockIdx.y, bn = blockIdx.x;
    const int lane = tid & 63, w = tid >> 6;      // 8 waves
    const int wm = w >> 2, wn = w & 3;            // 2 x 4 wave grid
    const int lr = lane & 15, lg = lane >> 4;

    const int srow = lane >> 3;
    const int sblk = (lane & 7) ^ srow;

    const unsigned short* gsrc[6];
    unsigned short* ldst[6];
    #pragma unroll
    for (int i = 0; i < 6; ++i) {
        int c = w * 6 + i;                        // wave-uniform
        if (c < 16) {
            gsrc[i] = A + (size_t)(bm*128 + c*8 + srow) * K + sblk*8;
            ldst[i] = sA + c*8*64;
        } else {
            gsrc[i] = Bt + (size_t)(bn*256 + (c-16)*8 + srow) * K + sblk*8;
            ldst[i] = sB + (size_t)(c-16)*8*64;
        }
    }

    f32x4 acc[4][4];
    #pragma unroll
    for (int m = 0; m < 4; ++m)
        #pragma unroll
        for (int n = 0; n < 4; ++n) acc[m][n] = (f32x4){0.f,0.f,0.f,0.f};

    for (int kt = 0; kt < K; kt += 64) {
        #pragma unroll
        for (int i = 0; i < 6; ++i) gload16(gsrc[i] + kt, ldst[i]);
        __syncthreads();

        #pragma unroll
        for (int kk = 0; kk < 64; kk += 32) {
            const int jj = lg + (kk >> 3);
            f16x8 af[4], bf[4];
            #pragma unroll
            for (int m = 0; m < 4; ++m) {
                int r = wm*64 + m*16 + lr;
                af[m] = *(const f16x8*)&sA[r*64 + ((jj ^ (r & 7)) << 3)];
            }
            #pragma unroll
            for (int n = 0; n < 4; ++n) {
                int r = wn*64 + n*16 + lr;
                bf[n] = *(const f16x8*)&sB[r*64 + ((jj ^ (r & 7)) << 3)];
            }
            #pragma unroll
            for (int m = 0; m < 4; ++m)
                #pragma unroll
                for (int n = 0; n < 4; ++n)
                    acc[m][n] = __builtin_amdgcn_mfma_f32_16x16x32_f16(af[m], bf[n], acc[m][n], 0, 0, 0);
        }
        __syncthreads();
    }

    #pragma unroll
    for (int n = 0; n < 4; ++n) {
        int col = bn*256 + wn*64 + n*16 + lr;
        float bb = bias[col];
        #pragma unroll
        for (int m = 0; m < 4; ++m) {
            int row0 = bm*128 + wm*64 + m*16 + lg*4;
            #pragma unroll
            for (int q = 0; q < 4; ++q) {
                float v = acc[m][n][q] + bb;
                if (relu) v = fmaxf(v, 0.f);
                f16 h = (f16)v;
                O[(size_t)(row0 + q) * N + col] = __builtin_bit_cast(unsigned short, h);
            }
        }
    }
}

// ---------------------------------------------------------------------------
// fp32 GEMM: BM=128 x BN=64 x BK=32, 4x8/thread. (round-13 proven form)
// ---------------------------------------------------------------------------
#define BM 128
#define BN 64
#define BK 32

__global__ __launch_bounds__(256, 4) void k_gemm(
    const float* __restrict__ A, const float* __restrict__ W,
    const float* __restrict__ bias, float* __restrict__ C,
    int M, int K, int Nn, int relu)
{
    __shared__ float As[BK][BM + 4];   // 16.9 KiB
    __shared__ float Bs[BK][BN];       //  8.2 KiB
    const int tid = threadIdx.x;
    const int bm = blockIdx.y, bn = blockIdx.x;
    const int tr = tid >> 3, tc = tid & 7;           // 32x8 threads, 4x8 each
    const int ar0 = tid >> 1, ac0 = (tid & 1) * 16;  // A-stage: 1 row x 4 float4
    const int bk0 = tid >> 3, bn0 = (tid & 7) * 8;   // B-stage: 1 row x 2 float4
    const float* Ab = A + (size_t)bm * BM * K;
    const float* Wb = W + (size_t)bn * BN;

    float acc[4][8];
    #pragma unroll
    for (int i = 0; i < 4; ++i)
        #pragma unroll
        for (int j = 0; j < 8; ++j) acc[i][j] = 0.f;

    for (int k0 = 0; k0 < K; k0 += BK) {
        float4 a0 = *(const float4*)(Ab + (size_t)ar0*K + k0 + ac0);
        float4 a1 = *(const float4*)(Ab + (size_t)ar0*K + k0 + ac0 + 4);
        float4 a2 = *(const float4*)(Ab + (size_t)ar0*K + k0 + ac0 + 8);
        float4 a3 = *(const float4*)(Ab + (size_t)ar0*K + k0 + ac0 + 12);
        float4 w0 = *(const float4*)(Wb + (size_t)(k0+bk0)*Nn + bn0);
        float4 w1 = *(const float4*)(Wb + (size_t)(k0+bk0)*Nn + bn0 + 4);
        As[ac0+ 0][ar0] = a0.x; As[ac0+ 1][ar0] = a0.y;
        As[ac0+ 2][ar0] = a0.z; As[ac0+ 3][ar0] = a0.w;
        As[ac0+ 4][ar0] = a1.x; As[ac0+ 5][ar0] = a1.y;
        As[ac0+ 6][ar0] = a1.z; As[ac0+ 7][ar0] = a1.w;
        As[ac0+ 8][ar0] = a2.x; As[ac0+ 9][ar0] = a2.y;
        As[ac0+10][ar0] = a2.z; As[ac0+11][ar0] = a2.w;
        As[ac0+12][ar0] = a3.x; As[ac0+13][ar0] = a3.y;
        As[ac0+14][ar0] = a3.z; As[ac0+15][ar0] = a3.w;
        *(float4*)&Bs[bk0][bn0]     = w0;
        *(float4*)&Bs[bk0][bn0 + 4] = w1;
        __syncthreads();
        #pragma unroll
        for (int kk = 0; kk < BK; ++kk) {
            float4 av  = *(const float4*)&As[kk][tr*4];
            float4 bv0 = *(const float4*)&Bs[kk][tc*8];
            float4 bv1 = *(const float4*)&Bs[kk][tc*8+4];
            float a[4] = {av.x, av.y, av.z, av.w};
            float b[8] = {bv0.x,bv0.y,bv0.z,bv0.w, bv1.x,bv1.y,bv1.z,bv1.w};
            #pragma unroll
            for (int i = 0; i < 4; ++i)
                #pragma unroll
                for (int j = 0; j < 8; ++j)
                    acc[i][j] = fmaf(a[i], b[j], acc[i][j]);
        }
        __syncthreads();
    }

    float bl[8];
    #pragma unroll
    for (int j = 0; j < 8; ++j) bl[j] = bias[(size_t)bn*BN + tc*8 + j];
    #pragma unroll
    for (int i = 0; i < 4; ++i) {
        int row = bm*BM + tr*4 + i;
        float v[8];
        #pragma unroll
        for (int j = 0; j < 8; ++j) {
            float x = acc[i][j] + bl[j];
            v[j] = relu ? fmaxf(x, 0.f) : x;
        }
        float* cr = C + (size_t)row*Nn + bn*BN + tc*8;
        *(float4*)(cr)     = make_float4(v[0],v[1],v[2],v[3]);
        *(float4*)(cr + 4) = make_float4(v[4],v[5],v[6],v[7]);
    }
}

// ---------------------------------------------------------------------------
// score from fp32 T4 (rescore path)
// ---------------------------------------------------------------------------
__global__ __launch_bounds__(256) void k_score(
    const float* __restrict__ T4, const float* __restrict__ hw2,
    const float* __restrict__ hb2, float* __restrict__ scores, int M)
{
    int wv = (blockIdx.x * 256 + threadIdx.x) >> 6;
    int lane = threadIdx.x & 63;
    if (wv >= M) return;
    const float* row = T4 + (size_t)wv * 384;
    float s = 0.f;
    #pragma unroll
    for (int j = 0; j < 384; j += 64) s = fmaf(row[j + lane], hw2[j + lane], s);
    for (int o = 32; o > 0; o >>= 1) s += __shfl_down(s, o, 64);
    if (lane == 0) scores[wv] = s + hb2[0];
}

// ---------------------------------------------------------------------------
// Stage 1 select: per-batch top-CAND via bitonic sort, 1024 threads.
// ---------------------------------------------------------------------------
#define TPAD 4096
__global__ __launch_bounds__(1024) void k_topcand(
    const float* __restrict__ scores, const int* __restrict__ offs,
    int* __restrict__ cand_g, int* __restrict__ cand_p)
{
    __shared__ uint64_t key[TPAD];   // 32 KiB
    int b = blockIdx.x, t = threadIdx.x;
    int off = offs[b];
    int cnt = min(offs[b+1] - off, MAXPB);

    for (int i = t; i < TPAD; i += 1024) {
        uint64_t k = 0;
        if (i < cnt)
            k = ((uint64_t)sortable(scores[off + i]) << 32) | (uint32_t)(~i);
        key[i] = k;
    }

    for (int ksz = 2; ksz <= TPAD; ksz <<= 1) {
        for (int j = ksz >> 1; j > 0; j >>= 1) {
            __syncthreads();
            #pragma unroll 2
            for (int i = t; i < TPAD; i += 1024) {
                int ix = i ^ j;
                if (ix > i) {
                    uint64_t a = key[i], c = key[ix];
                    bool up = (i & ksz) == 0;
                    if (up ? (a < c) : (a > c)) { key[i] = c; key[ix] = a; }
                }
            }
        }
    }
    __syncthreads();

    if (t < CAND) {
        if (t < cnt) {
            int pos = (int)(~(uint32_t)key[t]);
            cand_g[b*CAND + t] = off + pos;
            cand_p[b*CAND + t] = pos;
        } else {
            cand_g[b*CAND + t] = -1;
            cand_p[b*CAND + t] = MAXPB + t;
        }
    }
}

// ---------------------------------------------------------------------------
// Stage 2: final top-MT by fp32 score via bitonic.
// Key: [sortable(fscore):32][~pos:12][j:8]   (CAND=144 < 256 fits in j:8)
// ---------------------------------------------------------------------------
__global__ __launch_bounds__(256) void k_fsel(
    const float* __restrict__ fscores, const int* __restrict__ offs,
    const int* __restrict__ cand_g, const int* __restrict__ cand_p,
    const float* __restrict__ coords, const float* __restrict__ times,
    int* __restrict__ tok_src, float* __restrict__ out_cent,
    float* __restrict__ out_mask)
{
    __shared__ uint64_t key[256];
    int b = blockIdx.x, t = threadIdx.x;
    int cnt = min(offs[b+1] - offs[b], MAXPB);
    int cntc = min(cnt, CAND);

    uint64_t k = 0;
    if (t < cntc) {
        uint32_t s32 = sortable(fscores[b*CAND + t]);
        uint32_t pos = (uint32_t)cand_p[b*CAND + t];
        k = ((uint64_t)s32 << 32) | (((~pos) & 0xFFFu) << 8) | (uint32_t)t;
    }
    key[t] = k;

    for (int ksz = 2; ksz <= 256; ksz <<= 1) {
        for (int j = ksz >> 1; j > 0; j >>= 1) {
            __syncthreads();
            int ix = t ^ j;
            if (ix > t) {
                uint64_t a = key[t], c = key[ix];
                bool up = (t & ksz) == 0;
                if (up ? (a < c) : (a > c)) { key[t] = c; key[ix] = a; }
            }
        }
    }
    __syncthreads();

    if (t < MT) {
        if (t < cntc) {
            int j = (int)(key[t] & 0xFF);
            int row = b*CAND + j;
            int g = cand_g[row];
            tok_src[b*MT + t] = row;
            out_mask[b*MT + t] = 1.0f;
            *(float4*)&out_cent[(size_t)(b*MT + t) * 4] =
                make_float4(coords[(size_t)g*3+0], coords[(size_t)g*3+1],
                            coords[(size_t)g*3+2], times[g]);
        } else {
            tok_src[b*MT + t] = -1;
            out_mask[b*MT + t] = 0.0f;
            *(float4*)&out_cent[(size_t)(b*MT + t) * 4] = make_float4(0.f,0.f,0.f,0.f);
        }
    }
}

// gather tokens from candidate point_feats
__global__ __launch_bounds__(256) void k_tokens(const float* __restrict__ PFc,
                                                const int* __restrict__ tok_src,
                                                float* __restrict__ out)
{
    int i = blockIdx.x * 256 + threadIdx.x;   // 8192*192 float4
    int row = i / 192, c = i % 192;
    int src = tok_src[row];
    float4 v = make_float4(0.f,0.f,0.f,0.f);
    if (src >= 0) v = ((const float4*)PFc)[(size_t)src*192 + c];
    ((float4*)out)[(size_t)row*192 + c] = v;
}

// ---------------------------------------------------------------------------
extern "C" void kernel_launch(void* const* d_in, const int* in_sizes, int n_in,
                              void* d_out, int out_size, void* d_ws, size_t ws_size,
                              hipStream_t stream)
{
    const float* coords = (const float*)d_in[0];
    const float* feats  = (const float*)d_in[1];
    const float* times  = (const float*)d_in[2];
    const int*   bids   = (const int*)  d_in[3];
    const float* ln_g = (const float*)d_in[4];
    const float* ln_b = (const float*)d_in[5];
    const float* sw1  = (const float*)d_in[6];
    const float* sb1  = (const float*)d_in[7];
    const float* sw2  = (const float*)d_in[8];
    const float* sb2  = (const float*)d_in[9];
    const float* mw1  = (const float*)d_in[10];
    const float* mb1  = (const float*)d_in[11];
    const float* mw2  = (const float*)d_in[12];
    const float* mb2  = (const float*)d_in[13];
    const float* mw3  = (const float*)d_in[14];
    const float* mb3  = (const float*)d_in[15];
    const float* mw4  = (const float*)d_in[16];
    const float* mb4  = (const float*)d_in[17];
    const float* hw1  = (const float*)d_in[18];
    const float* hb1  = (const float*)d_in[19];
    const float* hw2  = (const float*)d_in[20];
    const float* hb2  = (const float*)d_in[21];

    float* out_tok  = (float*)d_out;
    float* out_cent = out_tok + (size_t)NB*MT*TD;
    float* out_mask = out_cent + (size_t)NB*MT*4;

    char* wsb = (char*)d_ws;
    size_t off = 0;
    auto alloc = [&](size_t bytes) {
        char* p = wsb + off;
        off = (off + bytes + 255) & ~(size_t)255;
        return p;
    };
    auto mx = [](size_t a, size_t b) { return a > b ? a : b; };

    int*   offs    = (int*)  alloc((NB + 1) * 4);
    float* scores  = (float*)alloc((size_t)NPTS * 4);
    float* fscores = (float*)alloc((size_t)MC * 4);
    int*   cand_g  = (int*)  alloc((size_t)MC * 4);
    int*   cand_p  = (int*)  alloc((size_t)MC * 4);
    int*   tok_src = (int*)  alloc((size_t)NB * MT * 4);
    unsigned short* wt1h = (unsigned short*)alloc((size_t)256 * 128 * 2);
    unsigned short* wt2h = (unsigned short*)alloc((size_t)512 * 256 * 2);
    unsigned short* wt3h = (unsigned short*)alloc((size_t)768 * 512 * 2);
    float* zero384 = (float*)alloc(384 * 4);
    float* wfused  = (float*)alloc((size_t)768 * 384 * 4);   // W' = mw4@hw1 (fp32)
    float* bfused  = (float*)alloc(384 * 4);                 // b' = mb4@hw1 + hb1
    unsigned short* wfh = (unsigned short*)alloc((size_t)384 * 768 * 2);  // W'^T f16
    size_t base = off;

    int Nc = 8192;
    const int cands[3] = {32768, 16384, 8192};
    for (int ci = 0; ci < 3; ++ci) {
        size_t n = cands[ci];
        size_t need = base
            + mx(n*128*2, (size_t)MC*96*4)
            + mx(n*256*2, (size_t)MC*256*4)
            + mx(n*512*2, (size_t)MC*512*4)
            + 2 * mx(n*768*2, (size_t)MC*768*4)
            + 6*256;
        if (need <= ws_size) { Nc = (int)n; break; }
    }
    char* B0 = alloc(mx((size_t)Nc*128*2, (size_t)MC*96*4));
    char* B1 = alloc(mx((size_t)Nc*256*2, (size_t)MC*256*4));
    char* B2 = alloc(mx((size_t)Nc*512*2, (size_t)MC*512*4));
    char* B3 = alloc(mx((size_t)Nc*768*2, (size_t)MC*768*4));
    char* B4 = alloc(mx((size_t)Nc*768*2, (size_t)MC*768*4));

    // ---------- setup ----------
    k_counts<<<1, 128, 0, stream>>>(bids, offs);
    k_cvtw<<<(256*128+255)/256, 256, 0, stream>>>(mw1, wt1h,  96, 256, 128);
    k_cvtw<<<(512*256+255)/256, 256, 0, stream>>>(mw2, wt2h, 256, 512, 256);
    k_cvtw<<<(768*512+255)/256, 256, 0, stream>>>(mw3, wt3h, 512, 768, 512);
    // fused head: W' = mw4 @ hw1 (768x384), b' = mb4 @ hw1 + hb1
    hipMemsetAsync(zero384, 0, 384 * 4, stream);
    k_gemm<<<dim3(6, 6), 256, 0, stream>>>(mw4, hw1, zero384, wfused, 768, 768, 384, 0);
    k_fuseb<<<3, 128, 0, stream>>>(mb4, hw1, hb1, bfused);
    k_cvtw<<<(384*768+255)/256, 256, 0, stream>>>(wfused, wfh, 768, 384, 768);

    // ---------- stage 1: pure-f16 MFMA scoring (mw4+hw1 folded, fused head) --
    {
        unsigned short* X   = (unsigned short*)B0;   // [Nc][128]
        unsigned short* H1h = (unsigned short*)B1;   // [Nc][256]
        unsigned short* H2h = (unsigned short*)B2;   // [Nc][512]
        unsigned short* H3h = (unsigned short*)B3;   // [Nc][768]
        for (int p0 = 0; p0 < NPTS; p0 += Nc) {
            int Mi = min(Nc, NPTS - p0);
            k_x96h<<<(Mi+255)/256, 256, 0, stream>>>(coords, feats, times, ln_g, ln_b,
                                                     sw1, sb1, sw2, sb2, hb2,
                                                     scores, p0, Mi, X);
            k_hgemm <<<dim3(2, Mi/128), 256, 0, stream>>>(X,   wt1h, mb1, H1h,
                                                          nullptr, nullptr, Mi, 128, 256, 1);
            k_hgemm2<<<dim3(2, Mi/128), 512, 0, stream>>>(H1h, wt2h, mb2, H2h, Mi, 256, 512, 1);
            k_hgemm2<<<dim3(3, Mi/128), 512, 0, stream>>>(H2h, wt3h, mb3, H3h, Mi, 512, 768, 1);
            k_hgemm <<<dim3(3, Mi/128), 256, 0, stream>>>(H3h, wfh,  bfused, nullptr,
                                                          hw2, scores + p0, Mi, 768, 384, 1);
        }
    }

    // ---------- stage 2: capture top-CAND per batch (bitonic, 1024 thr) ------
    k_topcand<<<NB, 1024, 0, stream>>>(scores, offs, cand_g, cand_p);

    // ---------- stage 3: fp32 rescore of candidates (exact path) ----------
    {
        float* X96 = (float*)B0;
        float* H1  = (float*)B1;
        float* H2  = (float*)B2;
        float* H3  = (float*)B3;
        float* PFc = (float*)B4;
        float* T4  = (float*)B2;           // H2 dead by head time
        k_x96f<<<MC/256, 256, 0, stream>>>(coords, feats, times, ln_g, ln_b,
                                           sw1, sb1, sw2, sb2, cand_g, MC, X96);
        k_gemm<<<dim3( 4, MC/128), 256, 0, stream>>>(X96, mw1, mb1, H1, MC,  96, 256, 1);
        k_gemm<<<dim3( 8, MC/128), 256, 0, stream>>>(H1,  mw2, mb2, H2, MC, 256, 512, 1);
        k_gemm<<<dim3(12, MC/128), 256, 0, stream>>>(H2,  mw3, mb3, H3, MC, 512, 768, 1);
        k_gemm<<<dim3(12, MC/128), 256, 0, stream>>>(H3,  mw4, mb4, PFc, MC, 768, 768, 0);
        k_gemm<<<dim3( 6, MC/128), 256, 0, stream>>>(PFc, hw1, hb1, T4, MC, 768, 384, 1);
        k_score<<<MC/4, 256, 0, stream>>>(T4, hw2, hb2, fscores, MC);

        // ---------- stage 4: final top-128 per batch (bitonic) ----------
        k_fsel<<<NB, 256, 0, stream>>>(fscores, offs, cand_g, cand_p,
                                       coords, times, tok_src, out_cent, out_mask);
        k_tokens<<<(NB*MT*192)/256, 256, 0, stream>>>(PFc, tok_src, out_tok);
    }
}